// Round 2
// baseline (7001.352 us; speedup 1.0000x reference)
//
#include <hip/hip_runtime.h>
#include <math.h>

// ---- constants from the reference ----
#define C_TP1_SS   0.125f          // 1/sqrt(64*1)
#define C_TP1_VV   0.1020620726f   // (1/sqrt(3))/sqrt(32*1)
#define C_TP1_SV   0.125f          // 1/sqrt(64*1)
#define C_TP1_VS   0.1767766953f   // 1/sqrt(32*1)
#define C_LIN_S    0.125f          // 1/sqrt(64)
#define C_LIN_V    0.1767766953f   // 1/sqrt(32)
#define C_TP2_SS   0.015625f       // 1/sqrt(64*64)
#define C_TP2_VV   0.0180421959f   // (1/sqrt(3))/32
#define C_TP2_SVVS 0.0220970869f   // 1/sqrt(2048)

__device__ __forceinline__ float sigmoidf_(float x) { return 1.f / (1.f + __expf(-x)); }

// ============ K_pre: per-node hoisted tp1 matvecs (VERIFIED via out0) ============
__global__ void k_pre(const float* __restrict__ ns, const float* __restrict__ nv,
                      const float* __restrict__ Wss, const float* __restrict__ Wvv,
                      const float* __restrict__ Wsv, const float* __restrict__ Wvs,
                      float4* __restrict__ pre4, int N)
{
    __shared__ float sWss[64 * 96];
    __shared__ float sWvv[32 * 96];
    __shared__ float sWsv[64 * 32];
    __shared__ float sWvs[32 * 32];
    __shared__ float sNS[4][64];
    __shared__ float sNV[4][96];
    int tid = threadIdx.x;
    for (int i = tid; i < 64 * 96; i += 256) sWss[i] = Wss[i];
    for (int i = tid; i < 32 * 96; i += 256) sWvv[i] = Wvv[i];
    for (int i = tid; i < 64 * 32; i += 256) sWsv[i] = Wsv[i];
    for (int i = tid; i < 32 * 32; i += 256) sWvs[i] = Wvs[i];
    __syncthreads();
    int wid = tid >> 6, lane = tid & 63;
    int gw = blockIdx.x * 4 + wid, nw = gridDim.x * 4;
    for (int n = gw; n < N; n += nw) {
        sNS[wid][lane] = ns[(size_t)n * 64 + lane];
        sNV[wid][lane] = nv[(size_t)n * 96 + lane];
        if (lane < 32) sNV[wid][64 + lane] = nv[(size_t)n * 96 + 64 + lane];
        {
            float p = 0.f, q0 = 0.f, q1 = 0.f, q2 = 0.f;
            for (int u = 0; u < 64; ++u) p += sNS[wid][u] * sWss[u * 96 + lane];
            for (int u = 0; u < 32; ++u) {
                float wv = sWvv[u * 96 + lane];
                q0 += sNV[wid][u * 3 + 0] * wv;
                q1 += sNV[wid][u * 3 + 1] * wv;
                q2 += sNV[wid][u * 3 + 2] * wv;
            }
            pre4[(size_t)n * 128 + lane] = make_float4(p, q0, q1, q2);
        }
        if (lane < 32) {
            int w = 64 + lane;
            float p = 0.f, q0 = 0.f, q1 = 0.f, q2 = 0.f;
            for (int u = 0; u < 64; ++u) p += sNS[wid][u] * sWss[u * 96 + w];
            for (int u = 0; u < 32; ++u) {
                float wv = sWvv[u * 96 + w];
                q0 += sNV[wid][u * 3 + 0] * wv;
                q1 += sNV[wid][u * 3 + 1] * wv;
                q2 += sNV[wid][u * 3 + 2] * wv;
            }
            pre4[(size_t)n * 128 + 64 + lane] = make_float4(p, q0, q1, q2);
        } else {
            int w = lane - 32;
            float s = 0.f, v0 = 0.f, v1 = 0.f, v2 = 0.f;
            for (int u = 0; u < 64; ++u) s += sNS[wid][u] * sWsv[u * 32 + w];
            for (int u = 0; u < 32; ++u) {
                float wv = sWvs[u * 32 + w];
                v0 += sNV[wid][u * 3 + 0] * wv;
                v1 += sNV[wid][u * 3 + 1] * wv;
                v2 += sNV[wid][u * 3 + 2] * wv;
            }
            pre4[(size_t)n * 128 + 96 + w] = make_float4(s, v0, v1, v2);
        }
    }
}

// ============ K_edge: gather PRE, gate, atomic-aggregate (VERIFIED via out0) ============
__global__ void k_edge(const float4* __restrict__ pre4, const float4* __restrict__ esh,
                       const int* __restrict__ erow, const int* __restrict__ ecol,
                       float* __restrict__ AGG, int E)
{
    int gtid = blockIdx.x * blockDim.x + threadIdx.x;
    int lane = threadIdx.x & 63;
    int gw = gtid >> 6, nw = (gridDim.x * blockDim.x) >> 6;
    for (int e = gw; e < E; e += nw) {
        int j = ecol[e];
        int r = erow[e];
        float4 sh = esh[e];
        float a = sh.x;
        const float4* pj = pre4 + (size_t)j * 128;
        float4 A = pj[lane];
        float4 X = pj[64 + lane];
        float ms  = C_TP1_SS * a * A.x + C_TP1_VV * (sh.y * A.y + sh.z * A.z + sh.w * A.w);
        float gs  = ms * sigmoidf_(ms);
        float msX = C_TP1_SS * a * X.x + C_TP1_VV * (sh.y * X.y + sh.z * X.z + sh.w * X.w);
        float sg  = sigmoidf_(msX);
        float sigw = __shfl(sg, lane & 31);
        float* ab = AGG + (size_t)r * 160;
        atomicAdd(ab + lane, gs);
        if (lane >= 32) {
            int w = lane - 32;
            float g0 = (C_TP1_SV * sh.y * X.x + C_TP1_VS * a * X.y) * sigw;
            float g1 = (C_TP1_SV * sh.z * X.x + C_TP1_VS * a * X.z) * sigw;
            float g2 = (C_TP1_SV * sh.w * X.x + C_TP1_VS * a * X.w) * sigw;
            atomicAdd(ab + 64 + w * 3 + 0, g0);
            atomicAdd(ab + 64 + w * 3 + 1, g1);
            atomicAdd(ab + 64 + w * 3 + 2, g2);
        }
    }
}

// ============ K_lin1: apply lin1 to aggregates, in place (VERIFIED via out0) ============
__global__ void k_lin1(float* __restrict__ AGG, const float* __restrict__ L1s,
                       const float* __restrict__ L1v, int N)
{
    __shared__ float sLs[64 * 64];
    __shared__ float sLv[32 * 32];
    __shared__ float sS[4][64];
    __shared__ float sV[4][96];
    int tid = threadIdx.x;
    for (int i = tid; i < 64 * 64; i += 256) sLs[i] = L1s[i];
    for (int i = tid; i < 32 * 32; i += 256) sLv[i] = L1v[i];
    __syncthreads();
    int wid = tid >> 6, lane = tid & 63;
    int gw = blockIdx.x * 4 + wid, nw = gridDim.x * 4;
    for (int n = gw; n < N; n += nw) {
        float* base = AGG + (size_t)n * 160;
        sS[wid][lane] = base[lane];
        sV[wid][lane] = base[64 + lane];
        if (lane < 32) sV[wid][64 + lane] = base[128 + lane];
        float acc = 0.f;
        for (int u = 0; u < 64; ++u) acc += sS[wid][u] * sLs[u * 64 + lane];
        float o0 = 0.f, o1 = 0.f, o2 = 0.f;
        if (lane < 32) {
            for (int u = 0; u < 32; ++u) {
                float wv = sLv[u * 32 + lane];
                o0 += sV[wid][u * 3 + 0] * wv;
                o1 += sV[wid][u * 3 + 1] * wv;
                o2 += sV[wid][u * 3 + 2] * wv;
            }
        }
        base[lane] = C_LIN_S * acc;
        if (lane < 32) {
            base[64 + lane * 3 + 0] = C_LIN_V * o0;
            base[64 + lane * 3 + 1] = C_LIN_V * o1;
            base[64 + lane * 3 + 2] = C_LIN_V * o2;
        }
    }
}

// ============ K4a: SOUT[n][96] = ss + vv tensor products (VERIFIED via out0 scalar path) ============
__global__ __launch_bounds__(256) void k4a(const float* __restrict__ ns, const float* __restrict__ nv,
                                           const float* __restrict__ AGG,
                                           const float* __restrict__ W2ss, const float* __restrict__ W2vv,
                                           float* __restrict__ SOUT, int N)
{
    __shared__ float sNsT[64 * 64];
    __shared__ float sAsT[64 * 64];
    __shared__ float sNvT[96 * 64];
    __shared__ float sAvT[96 * 64];
    __shared__ float sW[32 * 96];
    int tid = threadIdx.x;
    int base = blockIdx.x * 64;
    for (int i = tid; i < 4096; i += 256) {
        int m = i >> 6, u = i & 63;
        int n = base + m;
        sNsT[u * 64 + m] = (n < N) ? ns[(size_t)n * 64 + u] : 0.f;
        sAsT[u * 64 + m] = (n < N) ? AGG[(size_t)n * 160 + u] : 0.f;
    }
    for (int i = tid; i < 6144; i += 256) {
        int m = i / 96, uc = i % 96;
        int n = base + m;
        sNvT[uc * 64 + m] = (n < N) ? nv[(size_t)n * 96 + uc] : 0.f;
        sAvT[uc * 64 + m] = (n < N) ? AGG[(size_t)n * 160 + 64 + uc] : 0.f;
    }
    int tx = tid & 15, ty = tid >> 4;
    float acc[4][6];
#pragma unroll
    for (int m = 0; m < 4; ++m)
#pragma unroll
        for (int w = 0; w < 6; ++w) acc[m][w] = 0.f;

    for (int kc = 0; kc < 4096; kc += 32) {
        __syncthreads();
        for (int i = tid; i < 3072; i += 256) sW[i] = W2ss[(size_t)kc * 96 + i] * C_TP2_SS;
        __syncthreads();
#pragma unroll
        for (int kk = 0; kk < 32; ++kk) {
            int k = kc + kk;
            int u = k >> 6, v = k & 63;
            float a4[4], b4[4], w6[6];
            *(float4*)a4 = *(const float4*)&sNsT[u * 64 + tx * 4];
            *(float4*)b4 = *(const float4*)&sAsT[v * 64 + tx * 4];
            *(float2*)&w6[0] = *(const float2*)&sW[kk * 96 + ty * 6 + 0];
            *(float2*)&w6[2] = *(const float2*)&sW[kk * 96 + ty * 6 + 2];
            *(float2*)&w6[4] = *(const float2*)&sW[kk * 96 + ty * 6 + 4];
#pragma unroll
            for (int m = 0; m < 4; ++m) {
                float A = a4[m] * b4[m];
#pragma unroll
                for (int w = 0; w < 6; ++w) acc[m][w] += A * w6[w];
            }
        }
    }
    for (int kc = 0; kc < 1024; kc += 32) {
        __syncthreads();
        for (int i = tid; i < 3072; i += 256) sW[i] = W2vv[(size_t)kc * 96 + i] * C_TP2_VV;
        __syncthreads();
#pragma unroll
        for (int kk = 0; kk < 32; ++kk) {
            int k = kc + kk;
            int u = k >> 5, v = k & 31;
            float x0[4], x1[4], x2[4], y0[4], y1[4], y2[4], w6[6];
            *(float4*)x0 = *(const float4*)&sNvT[(u * 3 + 0) * 64 + tx * 4];
            *(float4*)x1 = *(const float4*)&sNvT[(u * 3 + 1) * 64 + tx * 4];
            *(float4*)x2 = *(const float4*)&sNvT[(u * 3 + 2) * 64 + tx * 4];
            *(float4*)y0 = *(const float4*)&sAvT[(v * 3 + 0) * 64 + tx * 4];
            *(float4*)y1 = *(const float4*)&sAvT[(v * 3 + 1) * 64 + tx * 4];
            *(float4*)y2 = *(const float4*)&sAvT[(v * 3 + 2) * 64 + tx * 4];
            *(float2*)&w6[0] = *(const float2*)&sW[kk * 96 + ty * 6 + 0];
            *(float2*)&w6[2] = *(const float2*)&sW[kk * 96 + ty * 6 + 2];
            *(float2*)&w6[4] = *(const float2*)&sW[kk * 96 + ty * 6 + 4];
#pragma unroll
            for (int m = 0; m < 4; ++m) {
                float A = x0[m] * y0[m] + x1[m] * y1[m] + x2[m] * y2[m];
#pragma unroll
                for (int w = 0; w < 6; ++w) acc[m][w] += A * w6[w];
            }
        }
    }
#pragma unroll
    for (int m = 0; m < 4; ++m) {
        int n = base + tx * 4 + m;
        if (n < N) {
#pragma unroll
            for (int w = 0; w < 6; ++w) SOUT[(size_t)n * 96 + ty * 6 + w] = acc[m][w];
        }
    }
}

// ============ K4b_simple: VOUT via direct per-node double loop (NEW, debug-grade) ============
// Each wave handles 2 nodes (one per 32-lane half); lane&31 = output w.
// v_out[w][c] = C * ( sum_{u<64,v<32} ns[u]*av[v][c]*Wsv[u][v][w]
//                  + sum_{u<32,v<64} nv[u][c]*as[v]*Wvs[u][v][w] )
__global__ __launch_bounds__(256) void k4b_simple(const float* __restrict__ ns, const float* __restrict__ nv,
                                                  const float* __restrict__ AGG,
                                                  const float* __restrict__ W2sv, const float* __restrict__ W2vs,
                                                  float* __restrict__ VOUT, int N)
{
    __shared__ float sNS[8][64];
    __shared__ float sNV[8][96];
    __shared__ float sAS[8][64];
    __shared__ float sAV[8][96];
    int tid = threadIdx.x;
    int wid = tid >> 6, lane = tid & 63;
    int p = lane >> 5;      // which node of the wave's pair
    int w = lane & 31;      // output index
    int slot = wid * 2 + p;
    int pairStride = gridDim.x * 4 * 2;
    for (int pb = (blockIdx.x * 4 + wid) * 2; pb < N; pb += pairStride) {
        int n = pb + p;
        bool valid = (n < N);
        for (int i = w; i < 64; i += 32) {
            sNS[slot][i] = valid ? ns[(size_t)n * 64 + i] : 0.f;
            sAS[slot][i] = valid ? AGG[(size_t)n * 160 + i] : 0.f;
        }
        for (int i = w; i < 96; i += 32) {
            sNV[slot][i] = valid ? nv[(size_t)n * 96 + i] : 0.f;
            sAV[slot][i] = valid ? AGG[(size_t)n * 160 + 64 + i] : 0.f;
        }
        // wave-synchronous: writes above are ordered before reads below within the wave
        float a0 = 0.f, a1 = 0.f, a2 = 0.f;
        for (int u = 0; u < 64; ++u) {
            float su = sNS[slot][u];
            const float* Wrow = W2sv + (size_t)u * 1024 + w;   // [u][v][w], v stride 32
#pragma unroll 4
            for (int v = 0; v < 32; ++v) {
                float t = su * Wrow[v * 32];
                a0 += t * sAV[slot][v * 3 + 0];
                a1 += t * sAV[slot][v * 3 + 1];
                a2 += t * sAV[slot][v * 3 + 2];
            }
        }
        for (int u = 0; u < 32; ++u) {
            float x0 = sNV[slot][u * 3 + 0];
            float x1 = sNV[slot][u * 3 + 1];
            float x2 = sNV[slot][u * 3 + 2];
            const float* Wrow = W2vs + (size_t)u * 2048 + w;   // [u][v][w], v stride 32
#pragma unroll 4
            for (int v = 0; v < 64; ++v) {
                float t = Wrow[v * 32] * sAS[slot][v];
                a0 += x0 * t;
                a1 += x1 * t;
                a2 += x2 * t;
            }
        }
        if (valid) {
            VOUT[(size_t)n * 96 + w * 3 + 0] = C_TP2_SVVS * a0;
            VOUT[(size_t)n * 96 + w * 3 + 1] = C_TP2_SVVS * a1;
            VOUT[(size_t)n * 96 + w * 3 + 2] = C_TP2_SVVS * a2;
        }
    }
}

// ============ K5: gate + lin2 + residual (vector gate via shuffles, NEW) ============
__global__ void k5(const float* __restrict__ SOUT, const float* __restrict__ VOUT,
                   const float* __restrict__ ns, const float* __restrict__ nv,
                   const float* __restrict__ L2s, const float* __restrict__ L2v,
                   float* __restrict__ out, int N)
{
    __shared__ float sLs[64 * 64];
    __shared__ float sLv[32 * 32];
    __shared__ float sGS[4][64];
    __shared__ float sGV[4][96];
    int tid = threadIdx.x;
    for (int i = tid; i < 64 * 64; i += 256) sLs[i] = L2s[i];
    for (int i = tid; i < 32 * 32; i += 256) sLv[i] = L2v[i];
    __syncthreads();
    int wid = tid >> 6, lane = tid & 63;
    int gw = blockIdx.x * 4 + wid, nw = gridDim.x * 4;
    for (int n = gw; n < N; n += nw) {
        float so = SOUT[(size_t)n * 96 + lane];
        float sig = 0.f;
        if (lane < 32) sig = sigmoidf_(SOUT[(size_t)n * 96 + 64 + lane]);
        float sigA = __shfl(sig, lane / 3);          // gate for entry idx = lane
        float sigB = __shfl(sig, (64 + lane) / 3);   // gate for entry idx = 64+lane (lane<32)
        sGS[wid][lane] = so * sigmoidf_(so);
        float v0 = VOUT[(size_t)n * 96 + lane];
        sGV[wid][lane] = v0 * sigA;
        if (lane < 32) {
            float v1 = VOUT[(size_t)n * 96 + 64 + lane];
            sGV[wid][64 + lane] = v1 * sigB;
        }
        float acc = 0.f;
        for (int u = 0; u < 64; ++u) acc += sGS[wid][u] * sLs[u * 64 + lane];
        out[(size_t)n * 64 + lane] = ns[(size_t)n * 64 + lane] + C_LIN_S * acc;
        if (lane < 32) {
            float a0 = 0.f, a1 = 0.f, a2 = 0.f;
            for (int u = 0; u < 32; ++u) {
                float wv = sLv[u * 32 + lane];
                a0 += sGV[wid][u * 3 + 0] * wv;
                a1 += sGV[wid][u * 3 + 1] * wv;
                a2 += sGV[wid][u * 3 + 2] * wv;
            }
            size_t ob = (size_t)N * 64 + (size_t)n * 96 + lane * 3;
            out[ob + 0] = nv[(size_t)n * 96 + lane * 3 + 0] + C_LIN_V * a0;
            out[ob + 1] = nv[(size_t)n * 96 + lane * 3 + 1] + C_LIN_V * a1;
            out[ob + 2] = nv[(size_t)n * 96 + lane * 3 + 2] + C_LIN_V * a2;
        }
    }
}

extern "C" void kernel_launch(void* const* d_in, const int* in_sizes, int n_in,
                              void* d_out, int out_size, void* d_ws, size_t ws_size,
                              hipStream_t stream)
{
    const float* node_s = (const float*)d_in[0];
    const float* node_v = (const float*)d_in[1];
    const float4* esh   = (const float4*)d_in[2];
    const int* erow     = (const int*)d_in[4];
    const int* ecol     = (const int*)d_in[5];
    const float* W1ss   = (const float*)d_in[6];
    const float* W1vv   = (const float*)d_in[7];
    const float* W1sv   = (const float*)d_in[8];
    const float* W1vs   = (const float*)d_in[9];
    const float* L1s    = (const float*)d_in[10];
    const float* L1v    = (const float*)d_in[11];
    const float* W2ss   = (const float*)d_in[12];
    const float* W2vv   = (const float*)d_in[13];
    const float* W2sv   = (const float*)d_in[14];
    const float* W2vs   = (const float*)d_in[15];
    const float* L2s    = (const float*)d_in[16];
    const float* L2v    = (const float*)d_in[17];
    int N = in_sizes[0] / 64;
    int E = in_sizes[4];

    float* PRE  = (float*)d_ws;                    // N*512 floats
    float* AGG  = PRE + (size_t)N * 512;           // N*160 floats
    float* SOUT = PRE;                             // reuse PRE after edge stage
    float* VOUT = PRE + (size_t)N * 96;

    hipMemsetAsync(AGG, 0, (size_t)N * 160 * sizeof(float), stream);
    k_pre<<<1024, 256, 0, stream>>>(node_s, node_v, W1ss, W1vv, W1sv, W1vs, (float4*)PRE, N);
    k_edge<<<4096, 256, 0, stream>>>((const float4*)PRE, esh, erow, ecol, AGG, E);
    k_lin1<<<1024, 256, 0, stream>>>(AGG, L1s, L1v, N);
    k4a<<<(N + 63) / 64, 256, 0, stream>>>(node_s, node_v, AGG, W2ss, W2vv, SOUT, N);
    k4b_simple<<<1024, 256, 0, stream>>>(node_s, node_v, AGG, W2sv, W2vs, VOUT, N);
    k5<<<1024, 256, 0, stream>>>(SOUT, VOUT, node_s, node_v, L2s, L2v, (float*)d_out, N);
}

// Round 3
// 4994.842 us; speedup vs baseline: 1.4017x; 1.4017x over previous
//
#include <hip/hip_runtime.h>
#include <math.h>

// ---- constants from the reference ----
#define C_TP1_SS   0.125f          // 1/sqrt(64*1)
#define C_TP1_VV   0.1020620726f   // (1/sqrt(3))/sqrt(32*1)
#define C_TP1_SV   0.125f          // 1/sqrt(64*1)
#define C_TP1_VS   0.1767766953f   // 1/sqrt(32*1)
#define C_LIN_S    0.125f          // 1/sqrt(64)
#define C_LIN_V    0.1767766953f   // 1/sqrt(32)
#define C_TP2_SS   0.015625f       // 1/sqrt(64*64)
#define C_TP2_VV   0.0180421959f   // (1/sqrt(3))/32
#define C_TP2_SVVS 0.0220970869f   // 1/sqrt(2048)

__device__ __forceinline__ float sigmoidf_(float x) { return 1.f / (1.f + __expf(-x)); }

// ============ K_pre: per-node hoisted tp1 matvecs (VERIFIED) ============
__global__ void k_pre(const float* __restrict__ ns, const float* __restrict__ nv,
                      const float* __restrict__ Wss, const float* __restrict__ Wvv,
                      const float* __restrict__ Wsv, const float* __restrict__ Wvs,
                      float4* __restrict__ pre4, int N)
{
    __shared__ float sWss[64 * 96];
    __shared__ float sWvv[32 * 96];
    __shared__ float sWsv[64 * 32];
    __shared__ float sWvs[32 * 32];
    __shared__ float sNS[4][64];
    __shared__ float sNV[4][96];
    int tid = threadIdx.x;
    for (int i = tid; i < 64 * 96; i += 256) sWss[i] = Wss[i];
    for (int i = tid; i < 32 * 96; i += 256) sWvv[i] = Wvv[i];
    for (int i = tid; i < 64 * 32; i += 256) sWsv[i] = Wsv[i];
    for (int i = tid; i < 32 * 32; i += 256) sWvs[i] = Wvs[i];
    __syncthreads();
    int wid = tid >> 6, lane = tid & 63;
    int gw = blockIdx.x * 4 + wid, nw = gridDim.x * 4;
    for (int n = gw; n < N; n += nw) {
        sNS[wid][lane] = ns[(size_t)n * 64 + lane];
        sNV[wid][lane] = nv[(size_t)n * 96 + lane];
        if (lane < 32) sNV[wid][64 + lane] = nv[(size_t)n * 96 + 64 + lane];
        {
            float p = 0.f, q0 = 0.f, q1 = 0.f, q2 = 0.f;
            for (int u = 0; u < 64; ++u) p += sNS[wid][u] * sWss[u * 96 + lane];
            for (int u = 0; u < 32; ++u) {
                float wv = sWvv[u * 96 + lane];
                q0 += sNV[wid][u * 3 + 0] * wv;
                q1 += sNV[wid][u * 3 + 1] * wv;
                q2 += sNV[wid][u * 3 + 2] * wv;
            }
            pre4[(size_t)n * 128 + lane] = make_float4(p, q0, q1, q2);
        }
        if (lane < 32) {
            int w = 64 + lane;
            float p = 0.f, q0 = 0.f, q1 = 0.f, q2 = 0.f;
            for (int u = 0; u < 64; ++u) p += sNS[wid][u] * sWss[u * 96 + w];
            for (int u = 0; u < 32; ++u) {
                float wv = sWvv[u * 96 + w];
                q0 += sNV[wid][u * 3 + 0] * wv;
                q1 += sNV[wid][u * 3 + 1] * wv;
                q2 += sNV[wid][u * 3 + 2] * wv;
            }
            pre4[(size_t)n * 128 + 64 + lane] = make_float4(p, q0, q1, q2);
        } else {
            int w = lane - 32;
            float s = 0.f, v0 = 0.f, v1 = 0.f, v2 = 0.f;
            for (int u = 0; u < 64; ++u) s += sNS[wid][u] * sWsv[u * 32 + w];
            for (int u = 0; u < 32; ++u) {
                float wv = sWvs[u * 32 + w];
                v0 += sNV[wid][u * 3 + 0] * wv;
                v1 += sNV[wid][u * 3 + 1] * wv;
                v2 += sNV[wid][u * 3 + 2] * wv;
            }
            pre4[(size_t)n * 128 + 96 + w] = make_float4(s, v0, v1, v2);
        }
    }
}

// ============ K_edge: gather PRE, gate, atomic-aggregate (VERIFIED) ============
__global__ void k_edge(const float4* __restrict__ pre4, const float4* __restrict__ esh,
                       const int* __restrict__ erow, const int* __restrict__ ecol,
                       float* __restrict__ AGG, int E)
{
    int gtid = blockIdx.x * blockDim.x + threadIdx.x;
    int lane = threadIdx.x & 63;
    int gw = gtid >> 6, nw = (gridDim.x * blockDim.x) >> 6;
    for (int e = gw; e < E; e += nw) {
        int j = ecol[e];
        int r = erow[e];
        float4 sh = esh[e];
        float a = sh.x;
        const float4* pj = pre4 + (size_t)j * 128;
        float4 A = pj[lane];
        float4 X = pj[64 + lane];
        float ms  = C_TP1_SS * a * A.x + C_TP1_VV * (sh.y * A.y + sh.z * A.z + sh.w * A.w);
        float gs  = ms * sigmoidf_(ms);
        float msX = C_TP1_SS * a * X.x + C_TP1_VV * (sh.y * X.y + sh.z * X.z + sh.w * X.w);
        float sg  = sigmoidf_(msX);
        float sigw = __shfl(sg, lane & 31);
        float* ab = AGG + (size_t)r * 160;
        atomicAdd(ab + lane, gs);
        if (lane >= 32) {
            int w = lane - 32;
            float g0 = (C_TP1_SV * sh.y * X.x + C_TP1_VS * a * X.y) * sigw;
            float g1 = (C_TP1_SV * sh.z * X.x + C_TP1_VS * a * X.z) * sigw;
            float g2 = (C_TP1_SV * sh.w * X.x + C_TP1_VS * a * X.w) * sigw;
            atomicAdd(ab + 64 + w * 3 + 0, g0);
            atomicAdd(ab + 64 + w * 3 + 1, g1);
            atomicAdd(ab + 64 + w * 3 + 2, g2);
        }
    }
}

// ============ K_lin1: apply lin1 to aggregates, in place (VERIFIED) ============
__global__ void k_lin1(float* __restrict__ AGG, const float* __restrict__ L1s,
                       const float* __restrict__ L1v, int N)
{
    __shared__ float sLs[64 * 64];
    __shared__ float sLv[32 * 32];
    __shared__ float sS[4][64];
    __shared__ float sV[4][96];
    int tid = threadIdx.x;
    for (int i = tid; i < 64 * 64; i += 256) sLs[i] = L1s[i];
    for (int i = tid; i < 32 * 32; i += 256) sLv[i] = L1v[i];
    __syncthreads();
    int wid = tid >> 6, lane = tid & 63;
    int gw = blockIdx.x * 4 + wid, nw = gridDim.x * 4;
    for (int n = gw; n < N; n += nw) {
        float* base = AGG + (size_t)n * 160;
        sS[wid][lane] = base[lane];
        sV[wid][lane] = base[64 + lane];
        if (lane < 32) sV[wid][64 + lane] = base[128 + lane];
        float acc = 0.f;
        for (int u = 0; u < 64; ++u) acc += sS[wid][u] * sLs[u * 64 + lane];
        float o0 = 0.f, o1 = 0.f, o2 = 0.f;
        if (lane < 32) {
            for (int u = 0; u < 32; ++u) {
                float wv = sLv[u * 32 + lane];
                o0 += sV[wid][u * 3 + 0] * wv;
                o1 += sV[wid][u * 3 + 1] * wv;
                o2 += sV[wid][u * 3 + 2] * wv;
            }
        }
        base[lane] = C_LIN_S * acc;
        if (lane < 32) {
            base[64 + lane * 3 + 0] = C_LIN_V * o0;
            base[64 + lane * 3 + 1] = C_LIN_V * o1;
            base[64 + lane * 3 + 2] = C_LIN_V * o2;
        }
    }
}

// ============ K4ab: fused stage-B tensor products, 32 nodes/block, 3 blocks/CU ============
// Phase A: SOUT[n][w], w<96 = ss (K=4096) + vv (K=1024)
// Phase B: VOUT[n][w*3+c], w<32 = sv (K=2048) + vs (K=2048)
__global__ __launch_bounds__(256, 3) void k4ab(const float* __restrict__ ns, const float* __restrict__ nv,
                                               const float* __restrict__ AGG,
                                               const float* __restrict__ W2ss, const float* __restrict__ W2vv,
                                               const float* __restrict__ W2sv, const float* __restrict__ W2vs,
                                               float* __restrict__ SOUT, float* __restrict__ VOUT, int N)
{
    __shared__ float sNsT[64 * 32];   // 8 KB  [u][node]
    __shared__ float sAsT[64 * 32];   // 8 KB
    __shared__ float sNvT[96 * 32];   // 12 KB [u*3+c][node]
    __shared__ float sAvT[96 * 32];   // 12 KB
    __shared__ float sW[3072];        // 12 KB weight chunk
    int tid = threadIdx.x;
    int base = blockIdx.x * 32;

    // ---- stage 32 nodes, transposed ----
    for (int i = tid; i < 2048; i += 256) {
        int m = i >> 6, u = i & 63;
        int n = base + m;
        sNsT[u * 32 + m] = (n < N) ? ns[(size_t)n * 64 + u] : 0.f;
        sAsT[u * 32 + m] = (n < N) ? AGG[(size_t)n * 160 + u] : 0.f;
    }
    for (int i = tid; i < 3072; i += 256) {
        int m = i / 96, uc = i % 96;
        int n = base + m;
        sNvT[uc * 32 + m] = (n < N) ? nv[(size_t)n * 96 + uc] : 0.f;
        sAvT[uc * 32 + m] = (n < N) ? AGG[(size_t)n * 160 + 64 + uc] : 0.f;
    }

    int tx = tid & 15, ty = tid >> 4;      // tx: node pair (2 nodes), ty: output group
    int nodeb = tx * 2;

    // ---------------- Phase A: SOUT (w = ty*6 + j) ----------------
    float accA[2][6];
#pragma unroll
    for (int m = 0; m < 2; ++m)
#pragma unroll
        for (int j = 0; j < 6; ++j) accA[m][j] = 0.f;

    // ss: K = 4096, k = u*64+v
    for (int kc = 0; kc < 4096; kc += 32) {
        __syncthreads();
        {
            const float4* src = (const float4*)(W2ss + (size_t)kc * 96);
            for (int i = tid; i < 768; i += 256) {
                float4 t = src[i];
                ((float4*)sW)[i] = make_float4(t.x * C_TP2_SS, t.y * C_TP2_SS, t.z * C_TP2_SS, t.w * C_TP2_SS);
            }
        }
        __syncthreads();
        int u = kc >> 6, v0 = kc & 63;
        float2 a = *(const float2*)&sNsT[u * 32 + nodeb];   // chunk-invariant
#pragma unroll
        for (int kk = 0; kk < 32; ++kk) {
            float2 b = *(const float2*)&sAsT[(v0 + kk) * 32 + nodeb];
            float w6[6];
            *(float2*)&w6[0] = *(const float2*)&sW[kk * 96 + ty * 6 + 0];
            *(float2*)&w6[2] = *(const float2*)&sW[kk * 96 + ty * 6 + 2];
            *(float2*)&w6[4] = *(const float2*)&sW[kk * 96 + ty * 6 + 4];
            float A0 = a.x * b.x, A1 = a.y * b.y;
#pragma unroll
            for (int j = 0; j < 6; ++j) { accA[0][j] += A0 * w6[j]; accA[1][j] += A1 * w6[j]; }
        }
    }
    // vv: K = 1024, k = u*32+v, A = dot3
    for (int kc = 0; kc < 1024; kc += 32) {
        __syncthreads();
        {
            const float4* src = (const float4*)(W2vv + (size_t)kc * 96);
            for (int i = tid; i < 768; i += 256) {
                float4 t = src[i];
                ((float4*)sW)[i] = make_float4(t.x * C_TP2_VV, t.y * C_TP2_VV, t.z * C_TP2_VV, t.w * C_TP2_VV);
            }
        }
        __syncthreads();
        int u = kc >> 5;
        float2 x0 = *(const float2*)&sNvT[(u * 3 + 0) * 32 + nodeb];
        float2 x1 = *(const float2*)&sNvT[(u * 3 + 1) * 32 + nodeb];
        float2 x2 = *(const float2*)&sNvT[(u * 3 + 2) * 32 + nodeb];
#pragma unroll
        for (int kk = 0; kk < 32; ++kk) {   // v = kk
            float2 y0 = *(const float2*)&sAvT[(kk * 3 + 0) * 32 + nodeb];
            float2 y1 = *(const float2*)&sAvT[(kk * 3 + 1) * 32 + nodeb];
            float2 y2 = *(const float2*)&sAvT[(kk * 3 + 2) * 32 + nodeb];
            float w6[6];
            *(float2*)&w6[0] = *(const float2*)&sW[kk * 96 + ty * 6 + 0];
            *(float2*)&w6[2] = *(const float2*)&sW[kk * 96 + ty * 6 + 2];
            *(float2*)&w6[4] = *(const float2*)&sW[kk * 96 + ty * 6 + 4];
            float A0 = x0.x * y0.x + x1.x * y1.x + x2.x * y2.x;
            float A1 = x0.y * y0.y + x1.y * y1.y + x2.y * y2.y;
#pragma unroll
            for (int j = 0; j < 6; ++j) { accA[0][j] += A0 * w6[j]; accA[1][j] += A1 * w6[j]; }
        }
    }
#pragma unroll
    for (int m = 0; m < 2; ++m) {
        int n = base + nodeb + m;
        if (n < N) {
#pragma unroll
            for (int j = 0; j < 6; ++j) SOUT[(size_t)n * 96 + ty * 6 + j] = accA[m][j];
        }
    }

    // ---------------- Phase B: VOUT (w = ty*2 + j) ----------------
    float accB[2][2][3];
#pragma unroll
    for (int m = 0; m < 2; ++m)
#pragma unroll
        for (int j = 0; j < 2; ++j)
#pragma unroll
            for (int c = 0; c < 3; ++c) accB[m][j][c] = 0.f;

    // sv: K = 2048, k = u*32+v; A_c = ns[u]*av[v][c]
    for (int kc = 0; kc < 2048; kc += 32) {
        __syncthreads();
        {
            const float4* src = (const float4*)(W2sv + (size_t)kc * 32);
            float4 t = src[tid];
            ((float4*)sW)[tid] = make_float4(t.x * C_TP2_SVVS, t.y * C_TP2_SVVS, t.z * C_TP2_SVVS, t.w * C_TP2_SVVS);
        }
        __syncthreads();
        int u = kc >> 5;
        float2 s = *(const float2*)&sNsT[u * 32 + nodeb];
#pragma unroll
        for (int kk = 0; kk < 32; ++kk) {   // v = kk
            float2 y0 = *(const float2*)&sAvT[(kk * 3 + 0) * 32 + nodeb];
            float2 y1 = *(const float2*)&sAvT[(kk * 3 + 1) * 32 + nodeb];
            float2 y2 = *(const float2*)&sAvT[(kk * 3 + 2) * 32 + nodeb];
            float2 w2 = *(const float2*)&sW[kk * 32 + ty * 2];
            float t0 = s.x * y0.x, t1 = s.x * y1.x, t2 = s.x * y2.x;
            accB[0][0][0] += t0 * w2.x; accB[0][0][1] += t1 * w2.x; accB[0][0][2] += t2 * w2.x;
            accB[0][1][0] += t0 * w2.y; accB[0][1][1] += t1 * w2.y; accB[0][1][2] += t2 * w2.y;
            t0 = s.y * y0.y; t1 = s.y * y1.y; t2 = s.y * y2.y;
            accB[1][0][0] += t0 * w2.x; accB[1][0][1] += t1 * w2.x; accB[1][0][2] += t2 * w2.x;
            accB[1][1][0] += t0 * w2.y; accB[1][1][1] += t1 * w2.y; accB[1][1][2] += t2 * w2.y;
        }
    }
    // vs: K = 2048, k = u*64+v; A_c = nv[u][c]*as[v]
    for (int kc = 0; kc < 2048; kc += 32) {
        __syncthreads();
        {
            const float4* src = (const float4*)(W2vs + (size_t)kc * 32);
            float4 t = src[tid];
            ((float4*)sW)[tid] = make_float4(t.x * C_TP2_SVVS, t.y * C_TP2_SVVS, t.z * C_TP2_SVVS, t.w * C_TP2_SVVS);
        }
        __syncthreads();
        int u = kc >> 6, v0 = kc & 63;
        float2 x0 = *(const float2*)&sNvT[(u * 3 + 0) * 32 + nodeb];
        float2 x1 = *(const float2*)&sNvT[(u * 3 + 1) * 32 + nodeb];
        float2 x2 = *(const float2*)&sNvT[(u * 3 + 2) * 32 + nodeb];
#pragma unroll
        for (int kk = 0; kk < 32; ++kk) {
            float2 aa = *(const float2*)&sAsT[(v0 + kk) * 32 + nodeb];
            float2 w2 = *(const float2*)&sW[kk * 32 + ty * 2];
            float t0 = x0.x * aa.x, t1 = x1.x * aa.x, t2 = x2.x * aa.x;
            accB[0][0][0] += t0 * w2.x; accB[0][0][1] += t1 * w2.x; accB[0][0][2] += t2 * w2.x;
            accB[0][1][0] += t0 * w2.y; accB[0][1][1] += t1 * w2.y; accB[0][1][2] += t2 * w2.y;
            t0 = x0.y * aa.y; t1 = x1.y * aa.y; t2 = x2.y * aa.y;
            accB[1][0][0] += t0 * w2.x; accB[1][0][1] += t1 * w2.x; accB[1][0][2] += t2 * w2.x;
            accB[1][1][0] += t0 * w2.y; accB[1][1][1] += t1 * w2.y; accB[1][1][2] += t2 * w2.y;
        }
    }
#pragma unroll
    for (int m = 0; m < 2; ++m) {
        int n = base + nodeb + m;
        if (n < N) {
#pragma unroll
            for (int j = 0; j < 2; ++j)
#pragma unroll
                for (int c = 0; c < 3; ++c)
                    VOUT[(size_t)n * 96 + (ty * 2 + j) * 3 + c] = accB[m][j][c];
        }
    }
}

// ============ K5: gate + lin2 + residual (VERIFIED) ============
__global__ void k5(const float* __restrict__ SOUT, const float* __restrict__ VOUT,
                   const float* __restrict__ ns, const float* __restrict__ nv,
                   const float* __restrict__ L2s, const float* __restrict__ L2v,
                   float* __restrict__ out, int N)
{
    __shared__ float sLs[64 * 64];
    __shared__ float sLv[32 * 32];
    __shared__ float sGS[4][64];
    __shared__ float sGV[4][96];
    int tid = threadIdx.x;
    for (int i = tid; i < 64 * 64; i += 256) sLs[i] = L2s[i];
    for (int i = tid; i < 32 * 32; i += 256) sLv[i] = L2v[i];
    __syncthreads();
    int wid = tid >> 6, lane = tid & 63;
    int gw = blockIdx.x * 4 + wid, nw = gridDim.x * 4;
    for (int n = gw; n < N; n += nw) {
        float so = SOUT[(size_t)n * 96 + lane];
        float sig = 0.f;
        if (lane < 32) sig = sigmoidf_(SOUT[(size_t)n * 96 + 64 + lane]);
        float sigA = __shfl(sig, lane / 3);
        float sigB = __shfl(sig, (64 + lane) / 3);
        sGS[wid][lane] = so * sigmoidf_(so);
        float v0 = VOUT[(size_t)n * 96 + lane];
        sGV[wid][lane] = v0 * sigA;
        if (lane < 32) {
            float v1 = VOUT[(size_t)n * 96 + 64 + lane];
            sGV[wid][64 + lane] = v1 * sigB;
        }
        float acc = 0.f;
        for (int u = 0; u < 64; ++u) acc += sGS[wid][u] * sLs[u * 64 + lane];
        out[(size_t)n * 64 + lane] = ns[(size_t)n * 64 + lane] + C_LIN_S * acc;
        if (lane < 32) {
            float a0 = 0.f, a1 = 0.f, a2 = 0.f;
            for (int u = 0; u < 32; ++u) {
                float wv = sLv[u * 32 + lane];
                a0 += sGV[wid][u * 3 + 0] * wv;
                a1 += sGV[wid][u * 3 + 1] * wv;
                a2 += sGV[wid][u * 3 + 2] * wv;
            }
            size_t ob = (size_t)N * 64 + (size_t)n * 96 + lane * 3;
            out[ob + 0] = nv[(size_t)n * 96 + lane * 3 + 0] + C_LIN_V * a0;
            out[ob + 1] = nv[(size_t)n * 96 + lane * 3 + 1] + C_LIN_V * a1;
            out[ob + 2] = nv[(size_t)n * 96 + lane * 3 + 2] + C_LIN_V * a2;
        }
    }
}

extern "C" void kernel_launch(void* const* d_in, const int* in_sizes, int n_in,
                              void* d_out, int out_size, void* d_ws, size_t ws_size,
                              hipStream_t stream)
{
    const float* node_s = (const float*)d_in[0];
    const float* node_v = (const float*)d_in[1];
    const float4* esh   = (const float4*)d_in[2];
    const int* erow     = (const int*)d_in[4];
    const int* ecol     = (const int*)d_in[5];
    const float* W1ss   = (const float*)d_in[6];
    const float* W1vv   = (const float*)d_in[7];
    const float* W1sv   = (const float*)d_in[8];
    const float* W1vs   = (const float*)d_in[9];
    const float* L1s    = (const float*)d_in[10];
    const float* L1v    = (const float*)d_in[11];
    const float* W2ss   = (const float*)d_in[12];
    const float* W2vv   = (const float*)d_in[13];
    const float* W2sv   = (const float*)d_in[14];
    const float* W2vs   = (const float*)d_in[15];
    const float* L2s    = (const float*)d_in[16];
    const float* L2v    = (const float*)d_in[17];
    int N = in_sizes[0] / 64;
    int E = in_sizes[4];

    float* PRE  = (float*)d_ws;                    // N*512 floats
    float* AGG  = PRE + (size_t)N * 512;           // N*160 floats
    float* SOUT = PRE;                             // reuse PRE after edge stage
    float* VOUT = PRE + (size_t)N * 96;

    hipMemsetAsync(AGG, 0, (size_t)N * 160 * sizeof(float), stream);
    k_pre<<<1024, 256, 0, stream>>>(node_s, node_v, W1ss, W1vv, W1sv, W1vs, (float4*)PRE, N);
    k_edge<<<4096, 256, 0, stream>>>((const float4*)PRE, esh, erow, ecol, AGG, E);
    k_lin1<<<1024, 256, 0, stream>>>(AGG, L1s, L1v, N);
    k4ab<<<(N + 31) / 32, 256, 0, stream>>>(node_s, node_v, AGG, W2ss, W2vv, W2sv, W2vs, SOUT, VOUT, N);
    k5<<<1024, 256, 0, stream>>>(SOUT, VOUT, node_s, node_v, L2s, L2v, (float*)d_out, N);
}

// Round 4
// 4946.477 us; speedup vs baseline: 1.4154x; 1.0098x over previous
//
#include <hip/hip_runtime.h>
#include <math.h>

// ---- constants from the reference ----
#define C_TP1_SS   0.125f          // 1/sqrt(64*1)
#define C_TP1_VV   0.1020620726f   // (1/sqrt(3))/sqrt(32*1)
#define C_TP1_SV   0.125f          // 1/sqrt(64*1)
#define C_TP1_VS   0.1767766953f   // 1/sqrt(32*1)
#define C_LIN_S    0.125f          // 1/sqrt(64)
#define C_LIN_V    0.1767766953f   // 1/sqrt(32)
#define C_TP2_SS   0.015625f       // 1/sqrt(64*64)
#define C_TP2_VV   0.0180421959f   // (1/sqrt(3))/32
#define C_TP2_SVVS 0.0220970869f   // 1/sqrt(2048)

__device__ __forceinline__ float sigmoidf_(float x) { return 1.f / (1.f + __expf(-x)); }

// ============ K_pre: per-node hoisted tp1 matvecs (VERIFIED) ============
__global__ void k_pre(const float* __restrict__ ns, const float* __restrict__ nv,
                      const float* __restrict__ Wss, const float* __restrict__ Wvv,
                      const float* __restrict__ Wsv, const float* __restrict__ Wvs,
                      float4* __restrict__ pre4, int N)
{
    __shared__ float sWss[64 * 96];
    __shared__ float sWvv[32 * 96];
    __shared__ float sWsv[64 * 32];
    __shared__ float sWvs[32 * 32];
    __shared__ float sNS[4][64];
    __shared__ float sNV[4][96];
    int tid = threadIdx.x;
    for (int i = tid; i < 64 * 96; i += 256) sWss[i] = Wss[i];
    for (int i = tid; i < 32 * 96; i += 256) sWvv[i] = Wvv[i];
    for (int i = tid; i < 64 * 32; i += 256) sWsv[i] = Wsv[i];
    for (int i = tid; i < 32 * 32; i += 256) sWvs[i] = Wvs[i];
    __syncthreads();
    int wid = tid >> 6, lane = tid & 63;
    int gw = blockIdx.x * 4 + wid, nw = gridDim.x * 4;
    for (int n = gw; n < N; n += nw) {
        sNS[wid][lane] = ns[(size_t)n * 64 + lane];
        sNV[wid][lane] = nv[(size_t)n * 96 + lane];
        if (lane < 32) sNV[wid][64 + lane] = nv[(size_t)n * 96 + 64 + lane];
        {
            float p = 0.f, q0 = 0.f, q1 = 0.f, q2 = 0.f;
            for (int u = 0; u < 64; ++u) p += sNS[wid][u] * sWss[u * 96 + lane];
            for (int u = 0; u < 32; ++u) {
                float wv = sWvv[u * 96 + lane];
                q0 += sNV[wid][u * 3 + 0] * wv;
                q1 += sNV[wid][u * 3 + 1] * wv;
                q2 += sNV[wid][u * 3 + 2] * wv;
            }
            pre4[(size_t)n * 128 + lane] = make_float4(p, q0, q1, q2);
        }
        if (lane < 32) {
            int w = 64 + lane;
            float p = 0.f, q0 = 0.f, q1 = 0.f, q2 = 0.f;
            for (int u = 0; u < 64; ++u) p += sNS[wid][u] * sWss[u * 96 + w];
            for (int u = 0; u < 32; ++u) {
                float wv = sWvv[u * 96 + w];
                q0 += sNV[wid][u * 3 + 0] * wv;
                q1 += sNV[wid][u * 3 + 1] * wv;
                q2 += sNV[wid][u * 3 + 2] * wv;
            }
            pre4[(size_t)n * 128 + 64 + lane] = make_float4(p, q0, q1, q2);
        } else {
            int w = lane - 32;
            float s = 0.f, v0 = 0.f, v1 = 0.f, v2 = 0.f;
            for (int u = 0; u < 64; ++u) s += sNS[wid][u] * sWsv[u * 32 + w];
            for (int u = 0; u < 32; ++u) {
                float wv = sWvs[u * 32 + w];
                v0 += sNV[wid][u * 3 + 0] * wv;
                v1 += sNV[wid][u * 3 + 1] * wv;
                v2 += sNV[wid][u * 3 + 2] * wv;
            }
            pre4[(size_t)n * 128 + 96 + w] = make_float4(s, v0, v1, v2);
        }
    }
}

// ============ K_edge: gather PRE, gate, atomic-aggregate (VERIFIED) ============
__global__ void k_edge(const float4* __restrict__ pre4, const float4* __restrict__ esh,
                       const int* __restrict__ erow, const int* __restrict__ ecol,
                       float* __restrict__ AGG, int E)
{
    int gtid = blockIdx.x * blockDim.x + threadIdx.x;
    int lane = threadIdx.x & 63;
    int gw = gtid >> 6, nw = (gridDim.x * blockDim.x) >> 6;
    for (int e = gw; e < E; e += nw) {
        int j = ecol[e];
        int r = erow[e];
        float4 sh = esh[e];
        float a = sh.x;
        const float4* pj = pre4 + (size_t)j * 128;
        float4 A = pj[lane];
        float4 X = pj[64 + lane];
        float ms  = C_TP1_SS * a * A.x + C_TP1_VV * (sh.y * A.y + sh.z * A.z + sh.w * A.w);
        float gs  = ms * sigmoidf_(ms);
        float msX = C_TP1_SS * a * X.x + C_TP1_VV * (sh.y * X.y + sh.z * X.z + sh.w * X.w);
        float sg  = sigmoidf_(msX);
        float sigw = __shfl(sg, lane & 31);
        float* ab = AGG + (size_t)r * 160;
        atomicAdd(ab + lane, gs);
        if (lane >= 32) {
            int w = lane - 32;
            float g0 = (C_TP1_SV * sh.y * X.x + C_TP1_VS * a * X.y) * sigw;
            float g1 = (C_TP1_SV * sh.z * X.x + C_TP1_VS * a * X.z) * sigw;
            float g2 = (C_TP1_SV * sh.w * X.x + C_TP1_VS * a * X.w) * sigw;
            atomicAdd(ab + 64 + w * 3 + 0, g0);
            atomicAdd(ab + 64 + w * 3 + 1, g1);
            atomicAdd(ab + 64 + w * 3 + 2, g2);
        }
    }
}

// ============ K_lin1: apply lin1 to aggregates, in place (VERIFIED) ============
__global__ void k_lin1(float* __restrict__ AGG, const float* __restrict__ L1s,
                       const float* __restrict__ L1v, int N)
{
    __shared__ float sLs[64 * 64];
    __shared__ float sLv[32 * 32];
    __shared__ float sS[4][64];
    __shared__ float sV[4][96];
    int tid = threadIdx.x;
    for (int i = tid; i < 64 * 64; i += 256) sLs[i] = L1s[i];
    for (int i = tid; i < 32 * 32; i += 256) sLv[i] = L1v[i];
    __syncthreads();
    int wid = tid >> 6, lane = tid & 63;
    int gw = blockIdx.x * 4 + wid, nw = gridDim.x * 4;
    for (int n = gw; n < N; n += nw) {
        float* base = AGG + (size_t)n * 160;
        sS[wid][lane] = base[lane];
        sV[wid][lane] = base[64 + lane];
        if (lane < 32) sV[wid][64 + lane] = base[128 + lane];
        float acc = 0.f;
        for (int u = 0; u < 64; ++u) acc += sS[wid][u] * sLs[u * 64 + lane];
        float o0 = 0.f, o1 = 0.f, o2 = 0.f;
        if (lane < 32) {
            for (int u = 0; u < 32; ++u) {
                float wv = sLv[u * 32 + lane];
                o0 += sV[wid][u * 3 + 0] * wv;
                o1 += sV[wid][u * 3 + 1] * wv;
                o2 += sV[wid][u * 3 + 2] * wv;
            }
        }
        base[lane] = C_LIN_S * acc;
        if (lane < 32) {
            base[64 + lane * 3 + 0] = C_LIN_V * o0;
            base[64 + lane * 3 + 1] = C_LIN_V * o1;
            base[64 + lane * 3 + 2] = C_LIN_V * o2;
        }
    }
}

// ============ K4ab v2: 64 nodes/block, per-phase panel restage, 4n x 6w register tiles ============
// Phase order ss -> sv -> vv -> vs swaps only one 24KB panel per transition.
// sX/sY: [row][node] transposed panels (row = u or u*3+c or v), stride 64.
// Thread: tx = tid&15 -> nodes tx*4..+3;  ty = tid>>4 ->
//   phase A (ss,vv): outputs w = ty*6..+5 (accA[4][6])
//   phase B (sv,vs): outputs w = ty*2..+1, all 3 c (accB[4][2][3])
__global__ __launch_bounds__(256, 2) void k4ab(const float* __restrict__ ns, const float* __restrict__ nv,
                                               const float* __restrict__ AGG,
                                               const float* __restrict__ W2ss, const float* __restrict__ W2vv,
                                               const float* __restrict__ W2sv, const float* __restrict__ W2vs,
                                               float* __restrict__ SOUT, float* __restrict__ VOUT, int N)
{
    __shared__ float sX[96 * 64];   // 24 KB
    __shared__ float sY[96 * 64];   // 24 KB
    __shared__ float sW[3072];      // 12 KB
    int tid = threadIdx.x;
    int base = blockIdx.x * 64;
    int tx = tid & 15, ty = tid >> 4;
    int nb = tx * 4;

    // ---- stage for ss: sX = ns (64 rows), sY = agg_s (64 rows) ----
    for (int i = tid; i < 4096; i += 256) {
        int m = i >> 6, r = i & 63;
        int n = base + m;
        sX[r * 64 + m] = (n < N) ? ns[(size_t)n * 64 + r] : 0.f;
        sY[r * 64 + m] = (n < N) ? AGG[(size_t)n * 160 + r] : 0.f;
    }

    float accA[4][6];
    float accB[4][2][3];
#pragma unroll
    for (int m = 0; m < 4; ++m) {
#pragma unroll
        for (int j = 0; j < 6; ++j) accA[m][j] = 0.f;
#pragma unroll
        for (int j = 0; j < 2; ++j)
#pragma unroll
            for (int c = 0; c < 3; ++c) accB[m][j][c] = 0.f;
    }

    // ================= phase ss: k = u*64+v, K=4096 =================
    for (int kc = 0; kc < 4096; kc += 32) {
        __syncthreads();
        {
            const float4* src = (const float4*)(W2ss + (size_t)kc * 96);
            for (int i = tid; i < 768; i += 256) {
                float4 t = src[i];
                ((float4*)sW)[i] = make_float4(t.x * C_TP2_SS, t.y * C_TP2_SS, t.z * C_TP2_SS, t.w * C_TP2_SS);
            }
        }
        __syncthreads();
        int u = kc >> 6, v0 = kc & 63;
        float a4[4];
        *(float4*)a4 = *(const float4*)&sX[u * 64 + nb];
#pragma unroll
        for (int kk = 0; kk < 32; ++kk) {
            float b4[4], w6[6];
            *(float4*)b4 = *(const float4*)&sY[(v0 + kk) * 64 + nb];
            *(float2*)&w6[0] = *(const float2*)&sW[kk * 96 + ty * 6 + 0];
            *(float2*)&w6[2] = *(const float2*)&sW[kk * 96 + ty * 6 + 2];
            *(float2*)&w6[4] = *(const float2*)&sW[kk * 96 + ty * 6 + 4];
#pragma unroll
            for (int m = 0; m < 4; ++m) {
                float A = a4[m] * b4[m];
#pragma unroll
                for (int j = 0; j < 6; ++j) accA[m][j] += A * w6[j];
            }
        }
    }

    // ---- restage sY <- agg_v (96 rows); sX keeps ns ----
    __syncthreads();
    for (int i = tid; i < 6144; i += 256) {
        int m = i / 96, r = i % 96;
        int n = base + m;
        sY[r * 64 + m] = (n < N) ? AGG[(size_t)n * 160 + 64 + r] : 0.f;
    }

    // ================= phase sv: k = u*32+v, K=2048 =================
    for (int kc = 0; kc < 2048; kc += 32) {
        __syncthreads();
        {
            const float4* src = (const float4*)(W2sv + (size_t)kc * 32);
            float4 t = src[tid];
            ((float4*)sW)[tid] = make_float4(t.x * C_TP2_SVVS, t.y * C_TP2_SVVS, t.z * C_TP2_SVVS, t.w * C_TP2_SVVS);
        }
        __syncthreads();
        int u = kc >> 5;
        float s4[4];
        *(float4*)s4 = *(const float4*)&sX[u * 64 + nb];
#pragma unroll
        for (int kk = 0; kk < 32; ++kk) {   // v = kk
            float y0[4], y1[4], y2[4];
            *(float4*)y0 = *(const float4*)&sY[(kk * 3 + 0) * 64 + nb];
            *(float4*)y1 = *(const float4*)&sY[(kk * 3 + 1) * 64 + nb];
            *(float4*)y2 = *(const float4*)&sY[(kk * 3 + 2) * 64 + nb];
            float2 w2 = *(const float2*)&sW[kk * 32 + ty * 2];
#pragma unroll
            for (int m = 0; m < 4; ++m) {
                float t0 = s4[m] * y0[m], t1 = s4[m] * y1[m], t2 = s4[m] * y2[m];
                accB[m][0][0] += t0 * w2.x; accB[m][0][1] += t1 * w2.x; accB[m][0][2] += t2 * w2.x;
                accB[m][1][0] += t0 * w2.y; accB[m][1][1] += t1 * w2.y; accB[m][1][2] += t2 * w2.y;
            }
        }
    }

    // ---- restage sX <- nv (96 rows); sY keeps agg_v ----
    __syncthreads();
    for (int i = tid; i < 6144; i += 256) {
        int m = i / 96, r = i % 96;
        int n = base + m;
        sX[r * 64 + m] = (n < N) ? nv[(size_t)n * 96 + r] : 0.f;
    }

    // ================= phase vv: k = u*32+v, K=1024 =================
    for (int kc = 0; kc < 1024; kc += 32) {
        __syncthreads();
        {
            const float4* src = (const float4*)(W2vv + (size_t)kc * 96);
            for (int i = tid; i < 768; i += 256) {
                float4 t = src[i];
                ((float4*)sW)[i] = make_float4(t.x * C_TP2_VV, t.y * C_TP2_VV, t.z * C_TP2_VV, t.w * C_TP2_VV);
            }
        }
        __syncthreads();
        int u = kc >> 5;
        float x0[4], x1[4], x2[4];
        *(float4*)x0 = *(const float4*)&sX[(u * 3 + 0) * 64 + nb];
        *(float4*)x1 = *(const float4*)&sX[(u * 3 + 1) * 64 + nb];
        *(float4*)x2 = *(const float4*)&sX[(u * 3 + 2) * 64 + nb];
#pragma unroll
        for (int kk = 0; kk < 32; ++kk) {   // v = kk
            float y0[4], y1[4], y2[4], w6[6];
            *(float4*)y0 = *(const float4*)&sY[(kk * 3 + 0) * 64 + nb];
            *(float4*)y1 = *(const float4*)&sY[(kk * 3 + 1) * 64 + nb];
            *(float4*)y2 = *(const float4*)&sY[(kk * 3 + 2) * 64 + nb];
            *(float2*)&w6[0] = *(const float2*)&sW[kk * 96 + ty * 6 + 0];
            *(float2*)&w6[2] = *(const float2*)&sW[kk * 96 + ty * 6 + 2];
            *(float2*)&w6[4] = *(const float2*)&sW[kk * 96 + ty * 6 + 4];
#pragma unroll
            for (int m = 0; m < 4; ++m) {
                float A = x0[m] * y0[m] + x1[m] * y1[m] + x2[m] * y2[m];
#pragma unroll
                for (int j = 0; j < 6; ++j) accA[m][j] += A * w6[j];
            }
        }
    }

    // ---- write SOUT (ss+vv complete) ----
#pragma unroll
    for (int m = 0; m < 4; ++m) {
        int n = base + nb + m;
        if (n < N) {
#pragma unroll
            for (int j = 0; j < 6; ++j) SOUT[(size_t)n * 96 + ty * 6 + j] = accA[m][j];
        }
    }

    // ---- restage sY <- agg_s (64 rows); sX keeps nv ----
    __syncthreads();
    for (int i = tid; i < 4096; i += 256) {
        int m = i >> 6, r = i & 63;
        int n = base + m;
        sY[r * 64 + m] = (n < N) ? AGG[(size_t)n * 160 + r] : 0.f;
    }

    // ================= phase vs: k = u*64+v, K=2048 =================
    for (int kc = 0; kc < 2048; kc += 32) {
        __syncthreads();
        {
            const float4* src = (const float4*)(W2vs + (size_t)kc * 32);
            float4 t = src[tid];
            ((float4*)sW)[tid] = make_float4(t.x * C_TP2_SVVS, t.y * C_TP2_SVVS, t.z * C_TP2_SVVS, t.w * C_TP2_SVVS);
        }
        __syncthreads();
        int u = kc >> 6, v0 = kc & 63;
        float x0[4], x1[4], x2[4];
        *(float4*)x0 = *(const float4*)&sX[(u * 3 + 0) * 64 + nb];
        *(float4*)x1 = *(const float4*)&sX[(u * 3 + 1) * 64 + nb];
        *(float4*)x2 = *(const float4*)&sX[(u * 3 + 2) * 64 + nb];
#pragma unroll
        for (int kk = 0; kk < 32; ++kk) {
            float aa[4];
            *(float4*)aa = *(const float4*)&sY[(v0 + kk) * 64 + nb];
            float2 w2 = *(const float2*)&sW[kk * 32 + ty * 2];
#pragma unroll
            for (int m = 0; m < 4; ++m) {
                float t0 = x0[m] * aa[m], t1 = x1[m] * aa[m], t2 = x2[m] * aa[m];
                accB[m][0][0] += t0 * w2.x; accB[m][0][1] += t1 * w2.x; accB[m][0][2] += t2 * w2.x;
                accB[m][1][0] += t0 * w2.y; accB[m][1][1] += t1 * w2.y; accB[m][1][2] += t2 * w2.y;
            }
        }
    }

    // ---- write VOUT (sv+vs complete) ----
#pragma unroll
    for (int m = 0; m < 4; ++m) {
        int n = base + nb + m;
        if (n < N) {
#pragma unroll
            for (int j = 0; j < 2; ++j)
#pragma unroll
                for (int c = 0; c < 3; ++c)
                    VOUT[(size_t)n * 96 + (ty * 2 + j) * 3 + c] = accB[m][j][c];
        }
    }
}

// ============ K5: gate + lin2 + residual (VERIFIED) ============
__global__ void k5(const float* __restrict__ SOUT, const float* __restrict__ VOUT,
                   const float* __restrict__ ns, const float* __restrict__ nv,
                   const float* __restrict__ L2s, const float* __restrict__ L2v,
                   float* __restrict__ out, int N)
{
    __shared__ float sLs[64 * 64];
    __shared__ float sLv[32 * 32];
    __shared__ float sGS[4][64];
    __shared__ float sGV[4][96];
    int tid = threadIdx.x;
    for (int i = tid; i < 64 * 64; i += 256) sLs[i] = L2s[i];
    for (int i = tid; i < 32 * 32; i += 256) sLv[i] = L2v[i];
    __syncthreads();
    int wid = tid >> 6, lane = tid & 63;
    int gw = blockIdx.x * 4 + wid, nw = gridDim.x * 4;
    for (int n = gw; n < N; n += nw) {
        float so = SOUT[(size_t)n * 96 + lane];
        float sig = 0.f;
        if (lane < 32) sig = sigmoidf_(SOUT[(size_t)n * 96 + 64 + lane]);
        float sigA = __shfl(sig, lane / 3);
        float sigB = __shfl(sig, (64 + lane) / 3);
        sGS[wid][lane] = so * sigmoidf_(so);
        float v0 = VOUT[(size_t)n * 96 + lane];
        sGV[wid][lane] = v0 * sigA;
        if (lane < 32) {
            float v1 = VOUT[(size_t)n * 96 + 64 + lane];
            sGV[wid][64 + lane] = v1 * sigB;
        }
        float acc = 0.f;
        for (int u = 0; u < 64; ++u) acc += sGS[wid][u] * sLs[u * 64 + lane];
        out[(size_t)n * 64 + lane] = ns[(size_t)n * 64 + lane] + C_LIN_S * acc;
        if (lane < 32) {
            float a0 = 0.f, a1 = 0.f, a2 = 0.f;
            for (int u = 0; u < 32; ++u) {
                float wv = sLv[u * 32 + lane];
                a0 += sGV[wid][u * 3 + 0] * wv;
                a1 += sGV[wid][u * 3 + 1] * wv;
                a2 += sGV[wid][u * 3 + 2] * wv;
            }
            size_t ob = (size_t)N * 64 + (size_t)n * 96 + lane * 3;
            out[ob + 0] = nv[(size_t)n * 96 + lane * 3 + 0] + C_LIN_V * a0;
            out[ob + 1] = nv[(size_t)n * 96 + lane * 3 + 1] + C_LIN_V * a1;
            out[ob + 2] = nv[(size_t)n * 96 + lane * 3 + 2] + C_LIN_V * a2;
        }
    }
}

extern "C" void kernel_launch(void* const* d_in, const int* in_sizes, int n_in,
                              void* d_out, int out_size, void* d_ws, size_t ws_size,
                              hipStream_t stream)
{
    const float* node_s = (const float*)d_in[0];
    const float* node_v = (const float*)d_in[1];
    const float4* esh   = (const float4*)d_in[2];
    const int* erow     = (const int*)d_in[4];
    const int* ecol     = (const int*)d_in[5];
    const float* W1ss   = (const float*)d_in[6];
    const float* W1vv   = (const float*)d_in[7];
    const float* W1sv   = (const float*)d_in[8];
    const float* W1vs   = (const float*)d_in[9];
    const float* L1s    = (const float*)d_in[10];
    const float* L1v    = (const float*)d_in[11];
    const float* W2ss   = (const float*)d_in[12];
    const float* W2vv   = (const float*)d_in[13];
    const float* W2sv   = (const float*)d_in[14];
    const float* W2vs   = (const float*)d_in[15];
    const float* L2s    = (const float*)d_in[16];
    const float* L2v    = (const float*)d_in[17];
    int N = in_sizes[0] / 64;
    int E = in_sizes[4];

    float* PRE  = (float*)d_ws;                    // N*512 floats
    float* AGG  = PRE + (size_t)N * 512;           // N*160 floats
    float* SOUT = PRE;                             // reuse PRE after edge stage
    float* VOUT = PRE + (size_t)N * 96;

    hipMemsetAsync(AGG, 0, (size_t)N * 160 * sizeof(float), stream);
    k_pre<<<1024, 256, 0, stream>>>(node_s, node_v, W1ss, W1vv, W1sv, W1vs, (float4*)PRE, N);
    k_edge<<<4096, 256, 0, stream>>>((const float4*)PRE, esh, erow, ecol, AGG, E);
    k_lin1<<<1024, 256, 0, stream>>>(AGG, L1s, L1v, N);
    k4ab<<<(N + 63) / 64, 256, 0, stream>>>(node_s, node_v, AGG, W2ss, W2vv, W2sv, W2vs, SOUT, VOUT, N);
    k5<<<1024, 256, 0, stream>>>(SOUT, VOUT, node_s, node_v, L2s, L2v, (float*)d_out, N);
}

// Round 5
// 2691.886 us; speedup vs baseline: 2.6009x; 1.8376x over previous
//
#include <hip/hip_runtime.h>
#include <math.h>

// ---- constants from the reference ----
#define C_TP1_SS   0.125f          // 1/sqrt(64*1)
#define C_TP1_VV   0.1020620726f   // (1/sqrt(3))/sqrt(32*1)
#define C_TP1_SV   0.125f          // 1/sqrt(64*1)
#define C_TP1_VS   0.1767766953f   // 1/sqrt(32*1)
#define C_LIN_S    0.125f          // 1/sqrt(64)
#define C_LIN_V    0.1767766953f   // 1/sqrt(32)
#define C_TP2_SS   0.015625f       // 1/sqrt(64*64)
#define C_TP2_VV   0.0180421959f   // (1/sqrt(3))/32
#define C_TP2_SVVS 0.0220970869f   // 1/sqrt(2048)

typedef __attribute__((ext_vector_type(8))) short short8;
typedef __attribute__((ext_vector_type(16))) float f32x16;

__device__ __forceinline__ float sigmoidf_(float x) { return 1.f / (1.f + __expf(-x)); }

__device__ __forceinline__ unsigned short f2bf(float f) {
    unsigned int x = __float_as_uint(f);
    unsigned int r = x + 0x7FFFu + ((x >> 16) & 1u);
    return (unsigned short)(r >> 16);
}

__device__ __forceinline__ short8 as_s8(int4 v) { union { int4 a; short8 b; } u_; u_.a = v; return u_.b; }

__device__ __forceinline__ short8 pack8(float a0, float a1, float a2, float a3,
                                        float a4, float a5, float a6, float a7) {
    union { int i[4]; short8 s; } u_;
    asm("v_cvt_pk_bf16_f32 %0, %1, %2" : "=v"(u_.i[0]) : "v"(a0), "v"(a1));
    asm("v_cvt_pk_bf16_f32 %0, %1, %2" : "=v"(u_.i[1]) : "v"(a2), "v"(a3));
    asm("v_cvt_pk_bf16_f32 %0, %1, %2" : "=v"(u_.i[2]) : "v"(a4), "v"(a5));
    asm("v_cvt_pk_bf16_f32 %0, %1, %2" : "=v"(u_.i[3]) : "v"(a6), "v"(a7));
    return u_.s;
}

// ============ K_pre: per-node hoisted tp1 matvecs (VERIFIED) ============
__global__ void k_pre(const float* __restrict__ ns, const float* __restrict__ nv,
                      const float* __restrict__ Wss, const float* __restrict__ Wvv,
                      const float* __restrict__ Wsv, const float* __restrict__ Wvs,
                      float4* __restrict__ pre4, int N)
{
    __shared__ float sWss[64 * 96];
    __shared__ float sWvv[32 * 96];
    __shared__ float sWsv[64 * 32];
    __shared__ float sWvs[32 * 32];
    __shared__ float sNS[4][64];
    __shared__ float sNV[4][96];
    int tid = threadIdx.x;
    for (int i = tid; i < 64 * 96; i += 256) sWss[i] = Wss[i];
    for (int i = tid; i < 32 * 96; i += 256) sWvv[i] = Wvv[i];
    for (int i = tid; i < 64 * 32; i += 256) sWsv[i] = Wsv[i];
    for (int i = tid; i < 32 * 32; i += 256) sWvs[i] = Wvs[i];
    __syncthreads();
    int wid = tid >> 6, lane = tid & 63;
    int gw = blockIdx.x * 4 + wid, nw = gridDim.x * 4;
    for (int n = gw; n < N; n += nw) {
        sNS[wid][lane] = ns[(size_t)n * 64 + lane];
        sNV[wid][lane] = nv[(size_t)n * 96 + lane];
        if (lane < 32) sNV[wid][64 + lane] = nv[(size_t)n * 96 + 64 + lane];
        {
            float p = 0.f, q0 = 0.f, q1 = 0.f, q2 = 0.f;
            for (int u = 0; u < 64; ++u) p += sNS[wid][u] * sWss[u * 96 + lane];
            for (int u = 0; u < 32; ++u) {
                float wv = sWvv[u * 96 + lane];
                q0 += sNV[wid][u * 3 + 0] * wv;
                q1 += sNV[wid][u * 3 + 1] * wv;
                q2 += sNV[wid][u * 3 + 2] * wv;
            }
            pre4[(size_t)n * 128 + lane] = make_float4(p, q0, q1, q2);
        }
        if (lane < 32) {
            int w = 64 + lane;
            float p = 0.f, q0 = 0.f, q1 = 0.f, q2 = 0.f;
            for (int u = 0; u < 64; ++u) p += sNS[wid][u] * sWss[u * 96 + w];
            for (int u = 0; u < 32; ++u) {
                float wv = sWvv[u * 96 + w];
                q0 += sNV[wid][u * 3 + 0] * wv;
                q1 += sNV[wid][u * 3 + 1] * wv;
                q2 += sNV[wid][u * 3 + 2] * wv;
            }
            pre4[(size_t)n * 128 + 64 + lane] = make_float4(p, q0, q1, q2);
        } else {
            int w = lane - 32;
            float s = 0.f, v0 = 0.f, v1 = 0.f, v2 = 0.f;
            for (int u = 0; u < 64; ++u) s += sNS[wid][u] * sWsv[u * 32 + w];
            for (int u = 0; u < 32; ++u) {
                float wv = sWvs[u * 32 + w];
                v0 += sNV[wid][u * 3 + 0] * wv;
                v1 += sNV[wid][u * 3 + 1] * wv;
                v2 += sNV[wid][u * 3 + 2] * wv;
            }
            pre4[(size_t)n * 128 + 96 + w] = make_float4(s, v0, v1, v2);
        }
    }
}

// ============ K_edge: gather PRE, gate, atomic-aggregate (VERIFIED) ============
__global__ void k_edge(const float4* __restrict__ pre4, const float4* __restrict__ esh,
                       const int* __restrict__ erow, const int* __restrict__ ecol,
                       float* __restrict__ AGG, int E)
{
    int gtid = blockIdx.x * blockDim.x + threadIdx.x;
    int lane = threadIdx.x & 63;
    int gw = gtid >> 6, nw = (gridDim.x * blockDim.x) >> 6;
    for (int e = gw; e < E; e += nw) {
        int j = ecol[e];
        int r = erow[e];
        float4 sh = esh[e];
        float a = sh.x;
        const float4* pj = pre4 + (size_t)j * 128;
        float4 A = pj[lane];
        float4 X = pj[64 + lane];
        float ms  = C_TP1_SS * a * A.x + C_TP1_VV * (sh.y * A.y + sh.z * A.z + sh.w * A.w);
        float gs  = ms * sigmoidf_(ms);
        float msX = C_TP1_SS * a * X.x + C_TP1_VV * (sh.y * X.y + sh.z * X.z + sh.w * X.w);
        float sg  = sigmoidf_(msX);
        float sigw = __shfl(sg, lane & 31);
        float* ab = AGG + (size_t)r * 160;
        atomicAdd(ab + lane, gs);
        if (lane >= 32) {
            int w = lane - 32;
            float g0 = (C_TP1_SV * sh.y * X.x + C_TP1_VS * a * X.y) * sigw;
            float g1 = (C_TP1_SV * sh.z * X.x + C_TP1_VS * a * X.z) * sigw;
            float g2 = (C_TP1_SV * sh.w * X.x + C_TP1_VS * a * X.w) * sigw;
            atomicAdd(ab + 64 + w * 3 + 0, g0);
            atomicAdd(ab + 64 + w * 3 + 1, g1);
            atomicAdd(ab + 64 + w * 3 + 2, g2);
        }
    }
}

// ============ K_lin1: apply lin1 to aggregates, in place (VERIFIED) ============
__global__ void k_lin1(float* __restrict__ AGG, const float* __restrict__ L1s,
                       const float* __restrict__ L1v, int N)
{
    __shared__ float sLs[64 * 64];
    __shared__ float sLv[32 * 32];
    __shared__ float sS[4][64];
    __shared__ float sV[4][96];
    int tid = threadIdx.x;
    for (int i = tid; i < 64 * 64; i += 256) sLs[i] = L1s[i];
    for (int i = tid; i < 32 * 32; i += 256) sLv[i] = L1v[i];
    __syncthreads();
    int wid = tid >> 6, lane = tid & 63;
    int gw = blockIdx.x * 4 + wid, nw = gridDim.x * 4;
    for (int n = gw; n < N; n += nw) {
        float* base = AGG + (size_t)n * 160;
        sS[wid][lane] = base[lane];
        sV[wid][lane] = base[64 + lane];
        if (lane < 32) sV[wid][64 + lane] = base[128 + lane];
        float acc = 0.f;
        for (int u = 0; u < 64; ++u) acc += sS[wid][u] * sLs[u * 64 + lane];
        float o0 = 0.f, o1 = 0.f, o2 = 0.f;
        if (lane < 32) {
            for (int u = 0; u < 32; ++u) {
                float wv = sLv[u * 32 + lane];
                o0 += sV[wid][u * 3 + 0] * wv;
                o1 += sV[wid][u * 3 + 1] * wv;
                o2 += sV[wid][u * 3 + 2] * wv;
            }
        }
        base[lane] = C_LIN_S * acc;
        if (lane < 32) {
            base[64 + lane * 3 + 0] = C_LIN_V * o0;
            base[64 + lane * 3 + 1] = C_LIN_V * o1;
            base[64 + lane * 3 + 2] = C_LIN_V * o2;
        }
    }
}

// ============ K_wprep: pack tp2 weights -> bf16, transposed [w][k], constants folded ============
// WT layout (ushort):
//   Wt_ss  [96][4096]  k = u*64+v              offset 0
//   Wt_vv  [96][3072]  k = c*1024 + u*32+v     offset 393216   (c-replicated)
//   Wt_sv  [32][2048]  k = u*32+v              offset 688128
//   Wt_vs  [32][2048]  k = u*64+v              offset 753664   total 819200
__global__ void k_wprep(const float* __restrict__ W2ss, const float* __restrict__ W2vv,
                        const float* __restrict__ W2sv, const float* __restrict__ W2vs,
                        unsigned short* __restrict__ WT)
{
    int i = blockIdx.x * 256 + threadIdx.x;
    if (i >= 819200) return;
    float val;
    if (i < 393216) {
        int w = i >> 12, k = i & 4095;
        val = W2ss[(size_t)k * 96 + w] * C_TP2_SS;
    } else if (i < 688128) {
        int j = i - 393216;
        int w = j / 3072, k = j % 3072;
        int q = k & 1023;                     // u*32+v  (c-major replication)
        val = W2vv[(size_t)q * 96 + w] * C_TP2_VV;
    } else if (i < 753664) {
        int j = i - 688128;
        int w = j >> 11, k = j & 2047;
        val = W2sv[(size_t)k * 32 + w] * C_TP2_SVVS;
    } else {
        int j = i - 753664;
        int w = j >> 11, k = j & 2047;
        val = W2vs[(size_t)k * 32 + w] * C_TP2_SVVS;
    }
    WT[i] = f2bf(val);
}

// ============ K4ab_mfma: stage-B tensor products via 32x32x16 bf16 MFMA ============
// 32 nodes/block, 4 waves, one phase per wave (0:ss 1:vv 2:sv 3:vs).
// LDS node operands (f32): NS[32][68] ns, AS[32][68] agg_s,
//                          NVt[32][100] nv as [c][u], AVt[32][100] agg_v as [c][v].
// A-frag (lane l): A[m=l&31][k=koff+(l>>5)*8+j] = x[m]*y[m][j]  (pack8 -> bf16x8)
// B-frag: Wt[w = tile*32 + (l&31)][koff+(l>>5)*8+j]  (16B global load, L2-resident)
// D (m74/m101): col = l&31 (=w), row = (r&3)+8*(r>>2)+4*(l>>5) (=node).
#define OFF_NS 0
#define OFF_AS 2176
#define OFF_NV 4352
#define OFF_AV 7552
__global__ __launch_bounds__(256, 3) void k4ab_mfma(const float* __restrict__ ns, const float* __restrict__ nv,
                                                    const float* __restrict__ AGG,
                                                    const unsigned short* __restrict__ WT,
                                                    float* __restrict__ SOUT, float* __restrict__ VOUT, int N)
{
    __shared__ float smem[10752];   // 43 KB
    const unsigned short* Wt_ss = WT;
    const unsigned short* Wt_vv = WT + 393216;
    const unsigned short* Wt_sv = WT + 688128;
    const unsigned short* Wt_vs = WT + 753664;

    int tid = threadIdx.x;
    int base = blockIdx.x * 32;

    // ---- stage node operands ----
    for (int i = tid; i < 2048; i += 256) {
        int mm = i >> 6, u = i & 63;
        int n = base + mm;
        smem[OFF_NS + mm * 68 + u] = (n < N) ? ns[(size_t)n * 64 + u] : 0.f;
        smem[OFF_AS + mm * 68 + u] = (n < N) ? AGG[(size_t)n * 160 + u] : 0.f;
    }
    for (int i = tid; i < 3072; i += 256) {
        int mm = i / 96, r = i % 96;
        int c = r >> 5, q = r & 31;
        int n = base + mm;
        smem[OFF_NV + mm * 100 + r] = (n < N) ? nv[(size_t)n * 96 + q * 3 + c] : 0.f;
        smem[OFF_AV + mm * 100 + r] = (n < N) ? AGG[(size_t)n * 160 + 64 + q * 3 + c] : 0.f;
    }
    __syncthreads();

    int wid = tid >> 6;
    int l = tid & 63;
    int m = l & 31;          // node-in-tile (A row) and w-in-tile (B/D col)
    int half = l >> 5;
    const float* pns = smem + OFF_NS + m * 68;
    const float* pas = smem + OFF_AS + m * 68;
    const float* pnv = smem + OFF_NV + m * 100;
    const float* pav = smem + OFF_AV + m * 100;

    f32x16 accA[3];   // wave0: ss SOUT tiles | wave1: vv SOUT tiles
    f32x16 accP[3];   // wave2: sv VOUT c-GEMMs | wave3: vs
#pragma unroll
    for (int a = 0; a < 3; ++a) {
#pragma unroll
        for (int r = 0; r < 16; ++r) { accA[a][r] = 0.f; accP[a][r] = 0.f; }
    }

    if (wid == 0) {
        // ---- ss: K=4096, k=u*64+v ----
#pragma unroll
        for (int nt = 0; nt < 3; ++nt) {
            f32x16 acc;
#pragma unroll
            for (int r = 0; r < 16; ++r) acc[r] = 0.f;
            const int4* bp = (const int4*)(Wt_ss + (size_t)(nt * 32 + m) * 4096 + half * 8);
            int4 b0 = bp[0], b1 = bp[2], b2 = bp[4], b3 = bp[6];
            for (int u = 0; u < 64; ++u) {
                const int4* bq = bp + (u + 1) * 8;   // next-u prefetch (in-bounds of ws)
                int4 n0 = bq[0], n1 = bq[2], n2 = bq[4], n3 = bq[6];
                float x = pns[u];
#pragma unroll
                for (int t = 0; t < 4; ++t) {
                    int v0 = t * 16 + half * 8;
                    float4 y0 = *(const float4*)&pas[v0];
                    float4 y1 = *(const float4*)&pas[v0 + 4];
                    short8 af = pack8(x * y0.x, x * y0.y, x * y0.z, x * y0.w,
                                      x * y1.x, x * y1.y, x * y1.z, x * y1.w);
                    int4 braw = (t == 0) ? b0 : (t == 1) ? b1 : (t == 2) ? b2 : b3;
                    acc = __builtin_amdgcn_mfma_f32_32x32x16_bf16(af, as_s8(braw), acc, 0, 0, 0);
                }
                b0 = n0; b1 = n1; b2 = n2; b3 = n3;
            }
            accA[nt] = acc;
        }
    } else if (wid == 1) {
        // ---- vv: K=3072, k=c*1024+u*32+v ----
#pragma unroll
        for (int nt = 0; nt < 3; ++nt) {
            f32x16 acc;
#pragma unroll
            for (int r = 0; r < 16; ++r) acc[r] = 0.f;
            const int4* bp = (const int4*)(Wt_vv + (size_t)(nt * 32 + m) * 3072 + half * 8);
#pragma unroll
            for (int c = 0; c < 3; ++c) {
                int4 b0 = bp[c * 128 + 0], b1 = bp[c * 128 + 2];
                for (int u = 0; u < 32; ++u) {
                    const int4* bq = bp + c * 128 + (u + 1) * 4;
                    int4 n0 = bq[0], n1 = bq[2];
                    float x = pnv[c * 32 + u];
#pragma unroll
                    for (int t = 0; t < 2; ++t) {
                        int v0 = t * 16 + half * 8;
                        float4 y0 = *(const float4*)&pav[c * 32 + v0];
                        float4 y1 = *(const float4*)&pav[c * 32 + v0 + 4];
                        short8 af = pack8(x * y0.x, x * y0.y, x * y0.z, x * y0.w,
                                          x * y1.x, x * y1.y, x * y1.z, x * y1.w);
                        int4 braw = (t == 0) ? b0 : b1;
                        acc = __builtin_amdgcn_mfma_f32_32x32x16_bf16(af, as_s8(braw), acc, 0, 0, 0);
                    }
                    b0 = n0; b1 = n1;
                }
            }
            accA[nt] = acc;
        }
    } else if (wid == 2) {
        // ---- sv: per c, K=2048, k=u*32+v ----
        const int4* bp = (const int4*)(Wt_sv + (size_t)m * 2048 + half * 8);
#pragma unroll
        for (int c = 0; c < 3; ++c) {
            f32x16 acc;
#pragma unroll
            for (int r = 0; r < 16; ++r) acc[r] = 0.f;
            int4 b0 = bp[0], b1 = bp[2];
            for (int u = 0; u < 64; ++u) {
                const int4* bq = bp + (u + 1) * 4;
                int4 n0 = bq[0], n1 = bq[2];
                float x = pns[u];
#pragma unroll
                for (int t = 0; t < 2; ++t) {
                    int v0 = t * 16 + half * 8;
                    float4 y0 = *(const float4*)&pav[c * 32 + v0];
                    float4 y1 = *(const float4*)&pav[c * 32 + v0 + 4];
                    short8 af = pack8(x * y0.x, x * y0.y, x * y0.z, x * y0.w,
                                      x * y1.x, x * y1.y, x * y1.z, x * y1.w);
                    int4 braw = (t == 0) ? b0 : b1;
                    acc = __builtin_amdgcn_mfma_f32_32x32x16_bf16(af, as_s8(braw), acc, 0, 0, 0);
                }
                b0 = n0; b1 = n1;
            }
            accP[c] = acc;
        }
    } else {
        // ---- vs: per c, K=2048, k=u*64+v ----
        const int4* bp = (const int4*)(Wt_vs + (size_t)m * 2048 + half * 8);
#pragma unroll
        for (int c = 0; c < 3; ++c) {
            f32x16 acc;
#pragma unroll
            for (int r = 0; r < 16; ++r) acc[r] = 0.f;
            int4 b0 = bp[0], b1 = bp[2], b2 = bp[4], b3 = bp[6];
            for (int u = 0; u < 32; ++u) {
                const int4* bq = bp + (u + 1) * 8;
                int4 n0 = bq[0], n1 = bq[2], n2 = bq[4], n3 = bq[6];
                float x = pnv[c * 32 + u];
#pragma unroll
                for (int t = 0; t < 4; ++t) {
                    int v0 = t * 16 + half * 8;
                    float4 y0 = *(const float4*)&pas[v0];
                    float4 y1 = *(const float4*)&pas[v0 + 4];
                    short8 af = pack8(x * y0.x, x * y0.y, x * y0.z, x * y0.w,
                                      x * y1.x, x * y1.y, x * y1.z, x * y1.w);
                    int4 braw = (t == 0) ? b0 : (t == 1) ? b1 : (t == 2) ? b2 : b3;
                    acc = __builtin_amdgcn_mfma_f32_32x32x16_bf16(af, as_s8(braw), acc, 0, 0, 0);
                }
                b0 = n0; b1 = n1; b2 = n2; b3 = n3;
            }
            accP[c] = acc;
        }
    }

    // ---- epilogue: ES = smem[0..3072) = SOUT tile [32][96]; EV = smem[3072..6144) = VOUT tile ----
    __syncthreads();
    if (wid == 0) {
#pragma unroll
        for (int nt = 0; nt < 3; ++nt)
#pragma unroll
            for (int r = 0; r < 16; ++r) {
                int row = (r & 3) + 8 * (r >> 2) + 4 * half;
                smem[row * 96 + nt * 32 + m] = accA[nt][r];
            }
    }
    if (wid == 2) {
#pragma unroll
        for (int c = 0; c < 3; ++c)
#pragma unroll
            for (int r = 0; r < 16; ++r) {
                int row = (r & 3) + 8 * (r >> 2) + 4 * half;
                smem[3072 + row * 96 + m * 3 + c] = accP[c][r];
            }
    }
    __syncthreads();
    if (wid == 1) {
#pragma unroll
        for (int nt = 0; nt < 3; ++nt)
#pragma unroll
            for (int r = 0; r < 16; ++r) {
                int row = (r & 3) + 8 * (r >> 2) + 4 * half;
                smem[row * 96 + nt * 32 + m] += accA[nt][r];
            }
    }
    if (wid == 3) {
#pragma unroll
        for (int c = 0; c < 3; ++c)
#pragma unroll
            for (int r = 0; r < 16; ++r) {
                int row = (r & 3) + 8 * (r >> 2) + 4 * half;
                smem[3072 + row * 96 + m * 3 + c] += accP[c][r];
            }
    }
    __syncthreads();
    for (int i = tid; i < 3072; i += 256) {
        int n = base + i / 96;
        if (n < N) SOUT[(size_t)n * 96 + i % 96] = smem[i];
    }
    for (int i = tid; i < 3072; i += 256) {
        int n = base + i / 96;
        if (n < N) VOUT[(size_t)n * 96 + i % 96] = smem[3072 + i];
    }
}

// ============ K5: gate + lin2 + residual (VERIFIED) ============
__global__ void k5(const float* __restrict__ SOUT, const float* __restrict__ VOUT,
                   const float* __restrict__ ns, const float* __restrict__ nv,
                   const float* __restrict__ L2s, const float* __restrict__ L2v,
                   float* __restrict__ out, int N)
{
    __shared__ float sLs[64 * 64];
    __shared__ float sLv[32 * 32];
    __shared__ float sGS[4][64];
    __shared__ float sGV[4][96];
    int tid = threadIdx.x;
    for (int i = tid; i < 64 * 64; i += 256) sLs[i] = L2s[i];
    for (int i = tid; i < 32 * 32; i += 256) sLv[i] = L2v[i];
    __syncthreads();
    int wid = tid >> 6, lane = tid & 63;
    int gw = blockIdx.x * 4 + wid, nw = gridDim.x * 4;
    for (int n = gw; n < N; n += nw) {
        float so = SOUT[(size_t)n * 96 + lane];
        float sig = 0.f;
        if (lane < 32) sig = sigmoidf_(SOUT[(size_t)n * 96 + 64 + lane]);
        float sigA = __shfl(sig, lane / 3);
        float sigB = __shfl(sig, (64 + lane) / 3);
        sGS[wid][lane] = so * sigmoidf_(so);
        float v0 = VOUT[(size_t)n * 96 + lane];
        sGV[wid][lane] = v0 * sigA;
        if (lane < 32) {
            float v1 = VOUT[(size_t)n * 96 + 64 + lane];
            sGV[wid][64 + lane] = v1 * sigB;
        }
        float acc = 0.f;
        for (int u = 0; u < 64; ++u) acc += sGS[wid][u] * sLs[u * 64 + lane];
        out[(size_t)n * 64 + lane] = ns[(size_t)n * 64 + lane] + C_LIN_S * acc;
        if (lane < 32) {
            float a0 = 0.f, a1 = 0.f, a2 = 0.f;
            for (int u = 0; u < 32; ++u) {
                float wv = sLv[u * 32 + lane];
                a0 += sGV[wid][u * 3 + 0] * wv;
                a1 += sGV[wid][u * 3 + 1] * wv;
                a2 += sGV[wid][u * 3 + 2] * wv;
            }
            size_t ob = (size_t)N * 64 + (size_t)n * 96 + lane * 3;
            out[ob + 0] = nv[(size_t)n * 96 + lane * 3 + 0] + C_LIN_V * a0;
            out[ob + 1] = nv[(size_t)n * 96 + lane * 3 + 1] + C_LIN_V * a1;
            out[ob + 2] = nv[(size_t)n * 96 + lane * 3 + 2] + C_LIN_V * a2;
        }
    }
}

extern "C" void kernel_launch(void* const* d_in, const int* in_sizes, int n_in,
                              void* d_out, int out_size, void* d_ws, size_t ws_size,
                              hipStream_t stream)
{
    const float* node_s = (const float*)d_in[0];
    const float* node_v = (const float*)d_in[1];
    const float4* esh   = (const float4*)d_in[2];
    const int* erow     = (const int*)d_in[4];
    const int* ecol     = (const int*)d_in[5];
    const float* W1ss   = (const float*)d_in[6];
    const float* W1vv   = (const float*)d_in[7];
    const float* W1sv   = (const float*)d_in[8];
    const float* W1vs   = (const float*)d_in[9];
    const float* L1s    = (const float*)d_in[10];
    const float* L1v    = (const float*)d_in[11];
    const float* W2ss   = (const float*)d_in[12];
    const float* W2vv   = (const float*)d_in[13];
    const float* W2sv   = (const float*)d_in[14];
    const float* W2vs   = (const float*)d_in[15];
    const float* L2s    = (const float*)d_in[16];
    const float* L2v    = (const float*)d_in[17];
    int N = in_sizes[0] / 64;
    int E = in_sizes[4];

    float* PRE  = (float*)d_ws;                    // N*512 floats (dead after k_edge)
    float* AGG  = PRE + (size_t)N * 512;           // N*160 floats
    float* SOUT = PRE;                             // N*96 floats (reuse PRE)
    float* VOUT = PRE + (size_t)N * 96;            // N*96 floats
    unsigned short* WT = (unsigned short*)(PRE + (size_t)N * 192);  // 819200 bf16, after SOUT/VOUT

    hipMemsetAsync(AGG, 0, (size_t)N * 160 * sizeof(float), stream);
    k_pre<<<1024, 256, 0, stream>>>(node_s, node_v, W1ss, W1vv, W1sv, W1vs, (float4*)PRE, N);
    k_edge<<<4096, 256, 0, stream>>>((const float4*)PRE, esh, erow, ecol, AGG, E);
    k_lin1<<<1024, 256, 0, stream>>>(AGG, L1s, L1v, N);
    k_wprep<<<3200, 256, 0, stream>>>(W2ss, W2vv, W2sv, W2vs, WT);
    k4ab_mfma<<<(N + 31) / 32, 256, 0, stream>>>(node_s, node_v, AGG, WT, SOUT, VOUT, N);
    k5<<<1024, 256, 0, stream>>>(SOUT, VOUT, node_s, node_v, L2s, L2v, (float*)d_out, N);
}

// Round 6
// 908.901 us; speedup vs baseline: 7.7031x; 2.9617x over previous
//
#include <hip/hip_runtime.h>
#include <math.h>

// ---- constants from the reference ----
#define C_TP1_SS   0.125f          // 1/sqrt(64*1)
#define C_TP1_VV   0.1020620726f   // (1/sqrt(3))/sqrt(32*1)
#define C_TP1_SV   0.125f          // 1/sqrt(64*1)
#define C_TP1_VS   0.1767766953f   // 1/sqrt(32*1)
#define C_LIN_S    0.125f          // 1/sqrt(64)
#define C_LIN_V    0.1767766953f   // 1/sqrt(32)
#define C_TP2_SS   0.015625f       // 1/sqrt(64*64)
#define C_TP2_VV   0.0180421959f   // (1/sqrt(3))/32
#define C_TP2_SVVS 0.0220970869f   // 1/sqrt(2048)

typedef __attribute__((ext_vector_type(8))) short short8;
typedef __attribute__((ext_vector_type(16))) float f32x16;

__device__ __forceinline__ float sigmoidf_(float x) { return 1.f / (1.f + __expf(-x)); }

__device__ __forceinline__ unsigned short f2bf(float f) {
    unsigned int x = __float_as_uint(f);
    unsigned int r = x + 0x7FFFu + ((x >> 16) & 1u);
    return (unsigned short)(r >> 16);
}

__device__ __forceinline__ unsigned int pack2(float lo, float hi) {
    unsigned int r;
    asm("v_cvt_pk_bf16_f32 %0, %1, %2" : "=v"(r) : "v"(lo), "v"(hi));
    return r;
}

__device__ __forceinline__ float blo(unsigned int v) { return __uint_as_float(v << 16); }
__device__ __forceinline__ float bhi(unsigned int v) { return __uint_as_float(v & 0xffff0000u); }

__device__ __forceinline__ short8 as_s8(int4 v) { union { int4 a; short8 b; } u_; u_.a = v; return u_.b; }

__device__ __forceinline__ short8 pack8(float a0, float a1, float a2, float a3,
                                        float a4, float a5, float a6, float a7) {
    union { int i[4]; short8 s; } u_;
    asm("v_cvt_pk_bf16_f32 %0, %1, %2" : "=v"(u_.i[0]) : "v"(a0), "v"(a1));
    asm("v_cvt_pk_bf16_f32 %0, %1, %2" : "=v"(u_.i[1]) : "v"(a2), "v"(a3));
    asm("v_cvt_pk_bf16_f32 %0, %1, %2" : "=v"(u_.i[2]) : "v"(a4), "v"(a5));
    asm("v_cvt_pk_bf16_f32 %0, %1, %2" : "=v"(u_.i[3]) : "v"(a6), "v"(a7));
    return u_.s;
}

// ============ K_pre v3: tiled GEMM, outputs bf16 PREb with tp1 constants folded ============
// PREb per node: 128 entries x 4 bf16 (8B): e<96: {C_SS*P1[e], C_VV*Q1[e][c]};
//                e=96+w: {C_SV*Ssv[w], C_VS*Vvs[w][c]}.
// 32 nodes/block; features transposed in LDS (stride 34); all W1 in LDS (48KB).
__global__ __launch_bounds__(256, 2) void k_pre(const float* __restrict__ ns, const float* __restrict__ nv,
                                                const float* __restrict__ Wss, const float* __restrict__ Wvv,
                                                const float* __restrict__ Wsv, const float* __restrict__ Wvs,
                                                unsigned short* __restrict__ PREb, int N)
{
    __shared__ float smem[17728];
    float* sWss = smem;            // 6144
    float* sWvv = smem + 6144;     // 3072
    float* sWsv = smem + 9216;     // 2048
    float* sWvs = smem + 11264;    // 1024
    float* nsT  = smem + 12288;    // 64*34
    float* nvT  = smem + 14464;    // 96*34
    int tid = threadIdx.x;
    int base = blockIdx.x * 32;

    for (int i = tid; i < 6144; i += 256) sWss[i] = Wss[i];
    for (int i = tid; i < 3072; i += 256) sWvv[i] = Wvv[i];
    for (int i = tid; i < 2048; i += 256) sWsv[i] = Wsv[i];
    for (int i = tid; i < 1024; i += 256) sWvs[i] = Wvs[i];
    for (int i = tid; i < 2048; i += 256) {
        int m = i >> 6, u = i & 63;
        int n = base + m;
        nsT[u * 34 + m] = (n < N) ? ns[(size_t)n * 64 + u] : 0.f;
    }
    for (int i = tid; i < 3072; i += 256) {
        int m = i / 96, f = i % 96;
        int u = f / 3, c = f % 3;
        int n = base + m;
        nvT[(c * 32 + u) * 34 + m] = (n < N) ? nv[(size_t)n * 96 + f] : 0.f;
    }
    __syncthreads();

    int tx = tid & 15, ty = tid >> 4;
    int m2 = tx * 2;
    int e6 = ty * 6, e2 = ty * 2;

    float pP[2][6] = {};
    float pQ[2][6][3] = {};
    float pS[2][2] = {};
    float pV[2][2][3] = {};

    // P (K=64) + S (K=64), shared feature read
    for (int u = 0; u < 64; ++u) {
        float2 x = *(const float2*)&nsT[u * 34 + m2];
        float w6[6];
        *(float2*)&w6[0] = *(const float2*)&sWss[u * 96 + e6 + 0];
        *(float2*)&w6[2] = *(const float2*)&sWss[u * 96 + e6 + 2];
        *(float2*)&w6[4] = *(const float2*)&sWss[u * 96 + e6 + 4];
        float2 w2 = *(const float2*)&sWsv[u * 32 + e2];
#pragma unroll
        for (int j = 0; j < 6; ++j) { pP[0][j] += x.x * w6[j]; pP[1][j] += x.y * w6[j]; }
        pS[0][0] += x.x * w2.x; pS[0][1] += x.x * w2.y;
        pS[1][0] += x.y * w2.x; pS[1][1] += x.y * w2.y;
    }
    // Q (K=32, 3c) + V (K=32, 3c), shared feature reads
    for (int u = 0; u < 32; ++u) {
        float2 x0 = *(const float2*)&nvT[(0 * 32 + u) * 34 + m2];
        float2 x1 = *(const float2*)&nvT[(1 * 32 + u) * 34 + m2];
        float2 x2 = *(const float2*)&nvT[(2 * 32 + u) * 34 + m2];
        float w6[6];
        *(float2*)&w6[0] = *(const float2*)&sWvv[u * 96 + e6 + 0];
        *(float2*)&w6[2] = *(const float2*)&sWvv[u * 96 + e6 + 2];
        *(float2*)&w6[4] = *(const float2*)&sWvv[u * 96 + e6 + 4];
        float2 w2 = *(const float2*)&sWvs[u * 32 + e2];
#pragma unroll
        for (int j = 0; j < 6; ++j) {
            pQ[0][j][0] += x0.x * w6[j]; pQ[1][j][0] += x0.y * w6[j];
            pQ[0][j][1] += x1.x * w6[j]; pQ[1][j][1] += x1.y * w6[j];
            pQ[0][j][2] += x2.x * w6[j]; pQ[1][j][2] += x2.y * w6[j];
        }
        pV[0][0][0] += x0.x * w2.x; pV[0][1][0] += x0.x * w2.y;
        pV[1][0][0] += x0.y * w2.x; pV[1][1][0] += x0.y * w2.y;
        pV[0][0][1] += x1.x * w2.x; pV[0][1][1] += x1.x * w2.y;
        pV[1][0][1] += x1.y * w2.x; pV[1][1][1] += x1.y * w2.y;
        pV[0][0][2] += x2.x * w2.x; pV[0][1][2] += x2.x * w2.y;
        pV[1][0][2] += x2.y * w2.x; pV[1][1][2] += x2.y * w2.y;
    }

    // epilogue: pack bf16 into LDS tile (overlay weight region), then coalesced copy
    __syncthreads();
    unsigned short* PT = (unsigned short*)smem;   // [32][512] ushort = 32 KB
#pragma unroll
    for (int m = 0; m < 2; ++m) {
        int nr = m2 + m;
#pragma unroll
        for (int j = 0; j < 6; ++j) {
            int e = e6 + j;
            unsigned int lo = pack2(C_TP1_SS * pP[m][j], C_TP1_VV * pQ[m][j][0]);
            unsigned int hi = pack2(C_TP1_VV * pQ[m][j][1], C_TP1_VV * pQ[m][j][2]);
            *(uint2*)&PT[nr * 512 + e * 4] = make_uint2(lo, hi);
        }
#pragma unroll
        for (int j = 0; j < 2; ++j) {
            int w = e2 + j;
            unsigned int lo = pack2(C_TP1_SV * pS[m][j], C_TP1_VS * pV[m][j][0]);
            unsigned int hi = pack2(C_TP1_VS * pV[m][j][1], C_TP1_VS * pV[m][j][2]);
            *(uint2*)&PT[nr * 512 + (96 + w) * 4] = make_uint2(lo, hi);
        }
    }
    __syncthreads();
    for (int i = tid; i < 2048; i += 256) {
        int n = base + (i >> 6);
        if (n < N) ((int4*)PREb)[(size_t)base * 64 + i] = ((const int4*)PT)[i];
    }
}

// ============ CSR build: histogram -> scan -> scatter ============
__global__ void k_hist(const int* __restrict__ erow, int* __restrict__ CNT, int E)
{
    int e = blockIdx.x * 256 + threadIdx.x;
    if (e < E) atomicAdd(&CNT[erow[e]], 1);
}

__global__ void k_scan(const int* __restrict__ CNT, int* __restrict__ OFFS, int N, int E)
{
    __shared__ int part[1024];
    int t = threadIdx.x;
    int chunk = (N + 1023) >> 10;
    int b0 = t * chunk; if (b0 > N) b0 = N;
    int b1 = b0 + chunk; if (b1 > N) b1 = N;
    int s = 0;
    for (int i = b0; i < b1; ++i) s += CNT[i];
    part[t] = s;
    __syncthreads();
    for (int off = 1; off < 1024; off <<= 1) {
        int v = (t >= off) ? part[t - off] : 0;
        __syncthreads();
        part[t] += v;
        __syncthreads();
    }
    int run = part[t] - s;
    for (int i = b0; i < b1; ++i) { OFFS[i] = run; run += CNT[i]; }
    if (t == 1023) OFFS[N] = E;
}

__global__ void k_scatter(const int* __restrict__ erow, const int* __restrict__ ecol,
                          const float4* __restrict__ esh, const int* __restrict__ OFFS,
                          int* __restrict__ CUR, int* __restrict__ EJ,
                          float4* __restrict__ ESHS, int E)
{
    int e = blockIdx.x * 256 + threadIdx.x;
    if (e >= E) return;
    int r = erow[e];
    int p = OFFS[r] + atomicAdd(&CUR[r], 1);
    EJ[p] = ecol[e];
    ESHS[p] = esh[e];
}

// ============ K_agg: one wave per node; gather bf16 PRE rows; register accumulate ============
// Lane l holds entries {2l, 2l+1} of the gathered node-j row.
//  lanes 0..31 : silu-gated scalar msgs w=2l,2l+1 -> AGG[r][2l..]
//  lanes 32..47: gate scalars (sigmoid) for w=2(l-32),2(l-32)+1 (shuffled out)
//  lanes 48..63: vector msgs w=2(l-48),2(l-48)+1 (x3 c) -> AGG[r][64+...]
__global__ void k_agg(const unsigned short* __restrict__ PREb, const int* __restrict__ EJ,
                      const float4* __restrict__ ESHS, const int* __restrict__ OFFS,
                      float* __restrict__ AGG, int N)
{
    int wv = blockIdx.x * 4 + (threadIdx.x >> 6);
    if (wv >= N) return;
    int lane = threadIdx.x & 63;
    int beg = OFFS[wv], end = OFFS[wv + 1];
    const int4* pb = (const int4*)PREb;
    float a0 = 0.f, a1 = 0.f;
    float b00 = 0.f, b01 = 0.f, b02 = 0.f, b10 = 0.f, b11 = 0.f, b12 = 0.f;
    int gsrc = (lane >= 48) ? (lane - 16) : lane;
    for (int i = beg; i < end; ++i) {
        int j = EJ[i];
        float4 sh = ESHS[i];
        int4 g = pb[(size_t)j * 64 + lane];
        unsigned int gx = (unsigned int)g.x, gy = (unsigned int)g.y;
        unsigned int gz = (unsigned int)g.z, gw = (unsigned int)g.w;
        float P0 = blo(gx), Q00 = bhi(gx), Q01 = blo(gy), Q02 = bhi(gy);
        float P1 = blo(gz), Q10 = bhi(gz), Q11 = blo(gw), Q12 = bhi(gw);
        float ms0 = sh.x * P0 + sh.y * Q00 + sh.z * Q01 + sh.w * Q02;
        float ms1 = sh.x * P1 + sh.y * Q10 + sh.z * Q11 + sh.w * Q12;
        float sg0 = sigmoidf_(ms0);
        float sg1 = sigmoidf_(ms1);
        float sw0 = __shfl(sg0, gsrc);
        float sw1 = __shfl(sg1, gsrc);
        if (lane < 32) {
            a0 += ms0 * sg0;
            a1 += ms1 * sg1;
        } else if (lane >= 48) {
            // entries are B[w]: P=S', Q0..2=V'c
            b00 += (sh.y * P0 + sh.x * Q00) * sw0;
            b01 += (sh.z * P0 + sh.x * Q01) * sw0;
            b02 += (sh.w * P0 + sh.x * Q02) * sw0;
            b10 += (sh.y * P1 + sh.x * Q10) * sw1;
            b11 += (sh.z * P1 + sh.x * Q11) * sw1;
            b12 += (sh.w * P1 + sh.x * Q12) * sw1;
        }
    }
    float* ab = AGG + (size_t)wv * 160;
    if (lane < 32) {
        *(float2*)&ab[2 * lane] = make_float2(a0, a1);
    } else if (lane >= 48) {
        int o = 64 + 6 * (lane - 48);
        *(float2*)&ab[o + 0] = make_float2(b00, b01);
        *(float2*)&ab[o + 2] = make_float2(b02, b10);
        *(float2*)&ab[o + 4] = make_float2(b11, b12);
    }
}

// ============ K_lin1: apply lin1 to aggregates, in place (VERIFIED) ============
__global__ void k_lin1(float* __restrict__ AGG, const float* __restrict__ L1s,
                       const float* __restrict__ L1v, int N)
{
    __shared__ float sLs[64 * 64];
    __shared__ float sLv[32 * 32];
    __shared__ float sS[4][64];
    __shared__ float sV[4][96];
    int tid = threadIdx.x;
    for (int i = tid; i < 64 * 64; i += 256) sLs[i] = L1s[i];
    for (int i = tid; i < 32 * 32; i += 256) sLv[i] = L1v[i];
    __syncthreads();
    int wid = tid >> 6, lane = tid & 63;
    int gw = blockIdx.x * 4 + wid, nw = gridDim.x * 4;
    for (int n = gw; n < N; n += nw) {
        float* base = AGG + (size_t)n * 160;
        sS[wid][lane] = base[lane];
        sV[wid][lane] = base[64 + lane];
        if (lane < 32) sV[wid][64 + lane] = base[128 + lane];
        float acc = 0.f;
        for (int u = 0; u < 64; ++u) acc += sS[wid][u] * sLs[u * 64 + lane];
        float o0 = 0.f, o1 = 0.f, o2 = 0.f;
        if (lane < 32) {
            for (int u = 0; u < 32; ++u) {
                float wv = sLv[u * 32 + lane];
                o0 += sV[wid][u * 3 + 0] * wv;
                o1 += sV[wid][u * 3 + 1] * wv;
                o2 += sV[wid][u * 3 + 2] * wv;
            }
        }
        base[lane] = C_LIN_S * acc;
        if (lane < 32) {
            base[64 + lane * 3 + 0] = C_LIN_V * o0;
            base[64 + lane * 3 + 1] = C_LIN_V * o1;
            base[64 + lane * 3 + 2] = C_LIN_V * o2;
        }
    }
}

// ============ K_wprep: pack tp2 weights -> bf16, transposed [w][k], constants folded (VERIFIED) ============
__global__ void k_wprep(const float* __restrict__ W2ss, const float* __restrict__ W2vv,
                        const float* __restrict__ W2sv, const float* __restrict__ W2vs,
                        unsigned short* __restrict__ WT)
{
    int i = blockIdx.x * 256 + threadIdx.x;
    if (i >= 819200) return;
    float val;
    if (i < 393216) {
        int w = i >> 12, k = i & 4095;
        val = W2ss[(size_t)k * 96 + w] * C_TP2_SS;
    } else if (i < 688128) {
        int j = i - 393216;
        int w = j / 3072, k = j % 3072;
        int q = k & 1023;
        val = W2vv[(size_t)q * 96 + w] * C_TP2_VV;
    } else if (i < 753664) {
        int j = i - 688128;
        int w = j >> 11, k = j & 2047;
        val = W2sv[(size_t)k * 32 + w] * C_TP2_SVVS;
    } else {
        int j = i - 753664;
        int w = j >> 11, k = j & 2047;
        val = W2vs[(size_t)k * 32 + w] * C_TP2_SVVS;
    }
    WT[i] = f2bf(val);
}

// ============ K4ab_mfma: stage-B tensor products via 32x32x16 bf16 MFMA (VERIFIED) ============
#define OFF_NS 0
#define OFF_AS 2176
#define OFF_NV 4352
#define OFF_AV 7552
__global__ __launch_bounds__(256, 3) void k4ab_mfma(const float* __restrict__ ns, const float* __restrict__ nv,
                                                    const float* __restrict__ AGG,
                                                    const unsigned short* __restrict__ WT,
                                                    float* __restrict__ SOUT, float* __restrict__ VOUT, int N)
{
    __shared__ float smem[10752];
    const unsigned short* Wt_ss = WT;
    const unsigned short* Wt_vv = WT + 393216;
    const unsigned short* Wt_sv = WT + 688128;
    const unsigned short* Wt_vs = WT + 753664;

    int tid = threadIdx.x;
    int base = blockIdx.x * 32;

    for (int i = tid; i < 2048; i += 256) {
        int mm = i >> 6, u = i & 63;
        int n = base + mm;
        smem[OFF_NS + mm * 68 + u] = (n < N) ? ns[(size_t)n * 64 + u] : 0.f;
        smem[OFF_AS + mm * 68 + u] = (n < N) ? AGG[(size_t)n * 160 + u] : 0.f;
    }
    for (int i = tid; i < 3072; i += 256) {
        int mm = i / 96, r = i % 96;
        int c = r >> 5, q = r & 31;
        int n = base + mm;
        smem[OFF_NV + mm * 100 + r] = (n < N) ? nv[(size_t)n * 96 + q * 3 + c] : 0.f;
        smem[OFF_AV + mm * 100 + r] = (n < N) ? AGG[(size_t)n * 160 + 64 + q * 3 + c] : 0.f;
    }
    __syncthreads();

    int wid = tid >> 6;
    int l = tid & 63;
    int m = l & 31;
    int half = l >> 5;
    const float* pns = smem + OFF_NS + m * 68;
    const float* pas = smem + OFF_AS + m * 68;
    const float* pnv = smem + OFF_NV + m * 100;
    const float* pav = smem + OFF_AV + m * 100;

    f32x16 accA[3];
    f32x16 accP[3];
#pragma unroll
    for (int a = 0; a < 3; ++a) {
#pragma unroll
        for (int r = 0; r < 16; ++r) { accA[a][r] = 0.f; accP[a][r] = 0.f; }
    }

    if (wid == 0) {
#pragma unroll
        for (int nt = 0; nt < 3; ++nt) {
            f32x16 acc;
#pragma unroll
            for (int r = 0; r < 16; ++r) acc[r] = 0.f;
            const int4* bp = (const int4*)(Wt_ss + (size_t)(nt * 32 + m) * 4096 + half * 8);
            int4 b0 = bp[0], b1 = bp[2], b2 = bp[4], b3 = bp[6];
            for (int u = 0; u < 64; ++u) {
                const int4* bq = bp + (u + 1) * 8;
                int4 n0 = bq[0], n1 = bq[2], n2 = bq[4], n3 = bq[6];
                float x = pns[u];
#pragma unroll
                for (int t = 0; t < 4; ++t) {
                    int v0 = t * 16 + half * 8;
                    float4 y0 = *(const float4*)&pas[v0];
                    float4 y1 = *(const float4*)&pas[v0 + 4];
                    short8 af = pack8(x * y0.x, x * y0.y, x * y0.z, x * y0.w,
                                      x * y1.x, x * y1.y, x * y1.z, x * y1.w);
                    int4 braw = (t == 0) ? b0 : (t == 1) ? b1 : (t == 2) ? b2 : b3;
                    acc = __builtin_amdgcn_mfma_f32_32x32x16_bf16(af, as_s8(braw), acc, 0, 0, 0);
                }
                b0 = n0; b1 = n1; b2 = n2; b3 = n3;
            }
            accA[nt] = acc;
        }
    } else if (wid == 1) {
#pragma unroll
        for (int nt = 0; nt < 3; ++nt) {
            f32x16 acc;
#pragma unroll
            for (int r = 0; r < 16; ++r) acc[r] = 0.f;
            const int4* bp = (const int4*)(Wt_vv + (size_t)(nt * 32 + m) * 3072 + half * 8);
#pragma unroll
            for (int c = 0; c < 3; ++c) {
                int4 b0 = bp[c * 128 + 0], b1 = bp[c * 128 + 2];
                for (int u = 0; u < 32; ++u) {
                    const int4* bq = bp + c * 128 + (u + 1) * 4;
                    int4 n0 = bq[0], n1 = bq[2];
                    float x = pnv[c * 32 + u];
#pragma unroll
                    for (int t = 0; t < 2; ++t) {
                        int v0 = t * 16 + half * 8;
                        float4 y0 = *(const float4*)&pav[c * 32 + v0];
                        float4 y1 = *(const float4*)&pav[c * 32 + v0 + 4];
                        short8 af = pack8(x * y0.x, x * y0.y, x * y0.z, x * y0.w,
                                          x * y1.x, x * y1.y, x * y1.z, x * y1.w);
                        int4 braw = (t == 0) ? b0 : b1;
                        acc = __builtin_amdgcn_mfma_f32_32x32x16_bf16(af, as_s8(braw), acc, 0, 0, 0);
                    }
                    b0 = n0; b1 = n1;
                }
            }
            accA[nt] = acc;
        }
    } else if (wid == 2) {
        const int4* bp = (const int4*)(Wt_sv + (size_t)m * 2048 + half * 8);
#pragma unroll
        for (int c = 0; c < 3; ++c) {
            f32x16 acc;
#pragma unroll
            for (int r = 0; r < 16; ++r) acc[r] = 0.f;
            int4 b0 = bp[0], b1 = bp[2];
            for (int u = 0; u < 64; ++u) {
                const int4* bq = bp + (u + 1) * 4;
                int4 n0 = bq[0], n1 = bq[2];
                float x = pns[u];
#pragma unroll
                for (int t = 0; t < 2; ++t) {
                    int v0 = t * 16 + half * 8;
                    float4 y0 = *(const float4*)&pav[c * 32 + v0];
                    float4 y1 = *(const float4*)&pav[c * 32 + v0 + 4];
                    short8 af = pack8(x * y0.x, x * y0.y, x * y0.z, x * y0.w,
                                      x * y1.x, x * y1.y, x * y1.z, x * y1.w);
                    int4 braw = (t == 0) ? b0 : b1;
                    acc = __builtin_amdgcn_mfma_f32_32x32x16_bf16(af, as_s8(braw), acc, 0, 0, 0);
                }
                b0 = n0; b1 = n1;
            }
            accP[c] = acc;
        }
    } else {
        const int4* bp = (const int4*)(Wt_vs + (size_t)m * 2048 + half * 8);
#pragma unroll
        for (int c = 0; c < 3; ++c) {
            f32x16 acc;
#pragma unroll
            for (int r = 0; r < 16; ++r) acc[r] = 0.f;
            int4 b0 = bp[0], b1 = bp[2], b2 = bp[4], b3 = bp[6];
            for (int u = 0; u < 32; ++u) {
                const int4* bq = bp + (u + 1) * 8;
                int4 n0 = bq[0], n1 = bq[2], n2 = bq[4], n3 = bq[6];
                float x = pnv[c * 32 + u];
#pragma unroll
                for (int t = 0; t < 4; ++t) {
                    int v0 = t * 16 + half * 8;
                    float4 y0 = *(const float4*)&pas[v0];
                    float4 y1 = *(const float4*)&pas[v0 + 4];
                    short8 af = pack8(x * y0.x, x * y0.y, x * y0.z, x * y0.w,
                                      x * y1.x, x * y1.y, x * y1.z, x * y1.w);
                    int4 braw = (t == 0) ? b0 : (t == 1) ? b1 : (t == 2) ? b2 : b3;
                    acc = __builtin_amdgcn_mfma_f32_32x32x16_bf16(af, as_s8(braw), acc, 0, 0, 0);
                }
                b0 = n0; b1 = n1; b2 = n2; b3 = n3;
            }
            accP[c] = acc;
        }
    }

    __syncthreads();
    if (wid == 0) {
#pragma unroll
        for (int nt = 0; nt < 3; ++nt)
#pragma unroll
            for (int r = 0; r < 16; ++r) {
                int row = (r & 3) + 8 * (r >> 2) + 4 * half;
                smem[row * 96 + nt * 32 + m] = accA[nt][r];
            }
    }
    if (wid == 2) {
#pragma unroll
        for (int c = 0; c < 3; ++c)
#pragma unroll
            for (int r = 0; r < 16; ++r) {
                int row = (r & 3) + 8 * (r >> 2) + 4 * half;
                smem[3072 + row * 96 + m * 3 + c] = accP[c][r];
            }
    }
    __syncthreads();
    if (wid == 1) {
#pragma unroll
        for (int nt = 0; nt < 3; ++nt)
#pragma unroll
            for (int r = 0; r < 16; ++r) {
                int row = (r & 3) + 8 * (r >> 2) + 4 * half;
                smem[row * 96 + nt * 32 + m] += accA[nt][r];
            }
    }
    if (wid == 3) {
#pragma unroll
        for (int c = 0; c < 3; ++c)
#pragma unroll
            for (int r = 0; r < 16; ++r) {
                int row = (r & 3) + 8 * (r >> 2) + 4 * half;
                smem[3072 + row * 96 + m * 3 + c] += accP[c][r];
            }
    }
    __syncthreads();
    for (int i = tid; i < 3072; i += 256) {
        int n = base + i / 96;
        if (n < N) SOUT[(size_t)n * 96 + i % 96] = smem[i];
    }
    for (int i = tid; i < 3072; i += 256) {
        int n = base + i / 96;
        if (n < N) VOUT[(size_t)n * 96 + i % 96] = smem[3072 + i];
    }
}

// ============ K5: gate + lin2 + residual (VERIFIED) ============
__global__ void k5(const float* __restrict__ SOUT, const float* __restrict__ VOUT,
                   const float* __restrict__ ns, const float* __restrict__ nv,
                   const float* __restrict__ L2s, const float* __restrict__ L2v,
                   float* __restrict__ out, int N)
{
    __shared__ float sLs[64 * 64];
    __shared__ float sLv[32 * 32];
    __shared__ float sGS[4][64];
    __shared__ float sGV[4][96];
    int tid = threadIdx.x;
    for (int i = tid; i < 64 * 64; i += 256) sLs[i] = L2s[i];
    for (int i = tid; i < 32 * 32; i += 256) sLv[i] = L2v[i];
    __syncthreads();
    int wid = tid >> 6, lane = tid & 63;
    int gw = blockIdx.x * 4 + wid, nw = gridDim.x * 4;
    for (int n = gw; n < N; n += nw) {
        float so = SOUT[(size_t)n * 96 + lane];
        float sig = 0.f;
        if (lane < 32) sig = sigmoidf_(SOUT[(size_t)n * 96 + 64 + lane]);
        float sigA = __shfl(sig, lane / 3);
        float sigB = __shfl(sig, (64 + lane) / 3);
        sGS[wid][lane] = so * sigmoidf_(so);
        float v0 = VOUT[(size_t)n * 96 + lane];
        sGV[wid][lane] = v0 * sigA;
        if (lane < 32) {
            float v1 = VOUT[(size_t)n * 96 + 64 + lane];
            sGV[wid][64 + lane] = v1 * sigB;
        }
        float acc = 0.f;
        for (int u = 0; u < 64; ++u) acc += sGS[wid][u] * sLs[u * 64 + lane];
        out[(size_t)n * 64 + lane] = ns[(size_t)n * 64 + lane] + C_LIN_S * acc;
        if (lane < 32) {
            float a0 = 0.f, a1 = 0.f, a2 = 0.f;
            for (int u = 0; u < 32; ++u) {
                float wv = sLv[u * 32 + lane];
                a0 += sGV[wid][u * 3 + 0] * wv;
                a1 += sGV[wid][u * 3 + 1] * wv;
                a2 += sGV[wid][u * 3 + 2] * wv;
            }
            size_t ob = (size_t)N * 64 + (size_t)n * 96 + lane * 3;
            out[ob + 0] = nv[(size_t)n * 96 + lane * 3 + 0] + C_LIN_V * a0;
            out[ob + 1] = nv[(size_t)n * 96 + lane * 3 + 1] + C_LIN_V * a1;
            out[ob + 2] = nv[(size_t)n * 96 + lane * 3 + 2] + C_LIN_V * a2;
        }
    }
}

extern "C" void kernel_launch(void* const* d_in, const int* in_sizes, int n_in,
                              void* d_out, int out_size, void* d_ws, size_t ws_size,
                              hipStream_t stream)
{
    const float* node_s = (const float*)d_in[0];
    const float* node_v = (const float*)d_in[1];
    const float4* esh   = (const float4*)d_in[2];
    const int* erow     = (const int*)d_in[4];
    const int* ecol     = (const int*)d_in[5];
    const float* W1ss   = (const float*)d_in[6];
    const float* W1vv   = (const float*)d_in[7];
    const float* W1sv   = (const float*)d_in[8];
    const float* W1vs   = (const float*)d_in[9];
    const float* L1s    = (const float*)d_in[10];
    const float* L1v    = (const float*)d_in[11];
    const float* W2ss   = (const float*)d_in[12];
    const float* W2vv   = (const float*)d_in[13];
    const float* W2sv   = (const float*)d_in[14];
    const float* W2vs   = (const float*)d_in[15];
    const float* L2s    = (const float*)d_in[16];
    const float* L2v    = (const float*)d_in[17];
    int N = in_sizes[0] / 64;
    int E = in_sizes[4];

    char* ws = (char*)d_ws;
    float* AGG            = (float*)ws;                                   // N*160 f32
    unsigned short* PREb  = (unsigned short*)(ws + (size_t)N * 640);      // N*512 bf16
    float* SOUT           = (float*)(ws + (size_t)N * 640);               // aliases PREb (dead then)
    float* VOUT           = (float*)(ws + (size_t)N * 640 + (size_t)N * 384);
    unsigned short* WT    = (unsigned short*)(ws + (size_t)N * 1664);     // 819200 bf16
    int* EJ               = (int*)(ws + (size_t)N * 1664 + 1638400);      // E int
    float4* ESHS          = (float4*)((char*)EJ + (size_t)E * 4);         // E float4
    int* CNT              = (int*)((char*)ESHS + (size_t)E * 16);         // N int
    int* OFFS             = CNT + N;                                      // N+16 int
    int* CUR              = OFFS + N + 16;                                // N int

    hipMemsetAsync(CNT, 0, (size_t)(3 * N + 16) * 4, stream);
    k_pre<<<(N + 31) / 32, 256, 0, stream>>>(node_s, node_v, W1ss, W1vv, W1sv, W1vs, PREb, N);
    k_hist<<<(E + 255) / 256, 256, 0, stream>>>(erow, CNT, E);
    k_scan<<<1, 1024, 0, stream>>>(CNT, OFFS, N, E);
    k_scatter<<<(E + 255) / 256, 256, 0, stream>>>(erow, ecol, esh, OFFS, CUR, EJ, ESHS, E);
    k_agg<<<(N + 3) / 4, 256, 0, stream>>>(PREb, EJ, ESHS, OFFS, AGG, N);
    k_lin1<<<1024, 256, 0, stream>>>(AGG, L1s, L1v, N);
    k_wprep<<<3200, 256, 0, stream>>>(W2ss, W2vv, W2sv, W2vs, WT);
    k4ab_mfma<<<(N + 31) / 32, 256, 0, stream>>>(node_s, node_v, AGG, WT, SOUT, VOUT, N);
    k5<<<1024, 256, 0, stream>>>(SOUT, VOUT, node_s, node_v, L2s, L2v, (float*)d_out, N);
}